// Round 2
// baseline (965.590 us; speedup 1.0000x reference)
//
#include <hip/hip_runtime.h>
#include <math.h>

#define B_   32
#define N_   1024
#define C_   4096
#define HC_  2048
#define D_   64
#define NT_  32768           // B*N tokens
#define KS_  8               // K splits for the P-GEMM
#define KC_  (HC_ / KS_)     // 256 columns per split
#define BKC_ 32              // K-chunk per staging step
#define RT_  128             // rows per k3 block

__device__ __forceinline__ float4 ld4(const float* p) {
    return *reinterpret_cast<const float4*>(p);
}

// ---------------------------------------------------------------------------
// K1: per-row LN stats + per-group accumulation of normalized upper half.
// All row data lives in registers across the stats barrier; gacc in registers
// (each thread owns 8 fixed upper columns); red[] double-buffered by row
// parity -> ONE barrier per row.  grid 4096 (= 32 b * 128 groups), block 256.
// ---------------------------------------------------------------------------
__global__ __launch_bounds__(256) void k1_stats(
        const float* __restrict__ x, const float* __restrict__ lnw,
        const float* __restrict__ lnb, float* __restrict__ muv,
        float* __restrict__ rsv, float* __restrict__ part) {
    __shared__ float red[2][4][2];   // [parity][wave][{s,q}]

    const int t = threadIdx.x;
    const int bid = blockIdx.x;
    const int b = bid >> 7;          // batch
    const int g = bid & 127;         // row group (8 rows)

    // this thread's 8 owned upper columns: HC_+t*4+e  and  HC_+1024+t*4+e
    const float4 wA = ld4(lnw + HC_ + t * 4);
    const float4 wB = ld4(lnw + HC_ + 1024 + t * 4);
    const float4 bA = ld4(lnb + HC_ + t * 4);
    const float4 bB = ld4(lnb + HC_ + 1024 + t * 4);

    float4 gA = make_float4(0.f, 0.f, 0.f, 0.f);
    float4 gB = make_float4(0.f, 0.f, 0.f, 0.f);

    for (int i = 0; i < 8; ++i) {
        const int n = g * 8 + i;
        const float* row = x + (size_t)(b * N_ + n) * C_;
        const float4 v0 = ld4(row + t * 4);
        const float4 v1 = ld4(row + 1024 + t * 4);
        const float4 v2 = ld4(row + 2048 + t * 4);   // upper, kept in regs
        const float4 v3 = ld4(row + 3072 + t * 4);   // upper, kept in regs

        float s = (v0.x + v0.y + v0.z + v0.w) + (v1.x + v1.y + v1.z + v1.w)
                + (v2.x + v2.y + v2.z + v2.w) + (v3.x + v3.y + v3.z + v3.w);
        float q = v0.x * v0.x + v0.y * v0.y + v0.z * v0.z + v0.w * v0.w;
        q = fmaf(v1.x, v1.x, fmaf(v1.y, v1.y, fmaf(v1.z, v1.z,
            fmaf(v1.w, v1.w, q))));
        q = fmaf(v2.x, v2.x, fmaf(v2.y, v2.y, fmaf(v2.z, v2.z,
            fmaf(v2.w, v2.w, q))));
        q = fmaf(v3.x, v3.x, fmaf(v3.y, v3.y, fmaf(v3.z, v3.z,
            fmaf(v3.w, v3.w, q))));

#pragma unroll
        for (int o = 32; o > 0; o >>= 1) {
            s += __shfl_down(s, o);
            q += __shfl_down(q, o);
        }
        if ((t & 63) == 0) {
            red[i & 1][t >> 6][0] = s;
            red[i & 1][t >> 6][1] = q;
        }
        __syncthreads();
        const float S = red[i & 1][0][0] + red[i & 1][1][0]
                      + red[i & 1][2][0] + red[i & 1][3][0];
        const float Q = red[i & 1][0][1] + red[i & 1][1][1]
                      + red[i & 1][2][1] + red[i & 1][3][1];
        const float mu = S * (1.f / C_);
        const float rs = rsqrtf(Q * (1.f / C_) - mu * mu + 1e-5f);
        if (t == 0) {
            muv[b * N_ + n] = mu;
            rsv[b * N_ + n] = rs;
        }
        gA.x += (v2.x - mu) * rs * wA.x + bA.x;
        gA.y += (v2.y - mu) * rs * wA.y + bA.y;
        gA.z += (v2.z - mu) * rs * wA.z + bA.z;
        gA.w += (v2.w - mu) * rs * wA.w + bA.w;
        gB.x += (v3.x - mu) * rs * wB.x + bB.x;
        gB.y += (v3.y - mu) * rs * wB.y + bB.y;
        gB.z += (v3.z - mu) * rs * wB.z + bB.z;
        gB.w += (v3.w - mu) * rs * wB.w + bB.w;
    }
    float* pp = part + (size_t)bid * HC_;
    *reinterpret_cast<float4*>(pp + t * 4) = gA;
    *reinterpret_cast<float4*>(pp + 1024 + t * 4) = gB;
}

// ---------------------------------------------------------------------------
// K1b: reduce 128 group partials -> G[b][j].  grid 256, block 256.
// ---------------------------------------------------------------------------
__global__ __launch_bounds__(256) void k1b_reduce(
        const float* __restrict__ part, float* __restrict__ G) {
    const int t = threadIdx.x;
    const int b = blockIdx.x >> 3;
    const int j = ((blockIdx.x & 7) << 8) + t;
    float a = 0.f;
    for (int g = 0; g < 128; ++g)
        a += part[(size_t)(b * 128 + g) * HC_ + j];
    G[b * HC_ + j] = a;
}

// ---------------------------------------------------------------------------
// K2: gterm[b,d] (b<32) and W1s/Bs (b==32).  grid 33, block 64.
// ---------------------------------------------------------------------------
__global__ __launch_bounds__(64) void k2_small(
        const float* __restrict__ G, const float* __restrict__ w1,
        const float* __restrict__ lnw, const float* __restrict__ lnb,
        float* __restrict__ gterm, float* __restrict__ W1s,
        float* __restrict__ Bs) {
    const int d = threadIdx.x;
    const int b = blockIdx.x;
    if (b < B_) {
        float a = 0.f;
        for (int j = 0; j < HC_; ++j)
            a = fmaf(G[b * HC_ + j], w1[(size_t)(HC_ + j) * D_ + d], a);
        gterm[b * D_ + d] = a * (1.f / N_);
    } else {
        float a = 0.f, c2 = 0.f;
        for (int c = 0; c < HC_; ++c) {
            float wv = w1[(size_t)c * D_ + d];
            a = fmaf(lnw[c], wv, a);
            c2 = fmaf(lnb[c], wv, c2);
        }
        W1s[d] = a;
        Bs[d] = c2;
    }
}

// ---------------------------------------------------------------------------
// K3: P-GEMM  P[t,d] = sum_c (x[t,c]*lnw[c]) * w1[c,d].
// 128 rows/block, 4 waves: wave pair (w>>1) -> 64-row group, (w&1) -> d-half.
// acc[32] per thread, xr read 4 cols at a time (small live range).
// w1 addresses are wave-uniform -> expect s_load.
// grid = KS_ * 256 = 2048, block 256.
// ---------------------------------------------------------------------------
__global__ __launch_bounds__(256) void k3_gemm(
        const float* __restrict__ x, const float* __restrict__ lnw,
        const float* __restrict__ w1, float* __restrict__ Pp) {
    __shared__ float xs[RT_ * BKC_];   // 16 KiB, XOR-swizzled rows of 128B

    const int t = threadIdx.x;
    const int mt = blockIdx.x & 255;   // M tile (128 rows)
    const int ks = blockIdx.x >> 8;    // K split
    const int T0 = mt * RT_;
    const int kbase = ks * KC_;
    const int w = t >> 6, lane = t & 63;
    const int rg = w >> 1;             // row group (0/1)
    const int dh = (w & 1) * 32;       // d-half offset
    const int myr = rg * 64 + lane;

    float acc[32];
#pragma unroll
    for (int d = 0; d < 32; ++d) acc[d] = 0.f;

    for (int kc = 0; kc < KC_; kc += BKC_) {
        const int k0 = kbase + kc;
        // --- stage 128 rows x 32 cols, folding ln_w ---
#pragma unroll
        for (int p = 0; p < 4; ++p) {
            const int r = p * 32 + (t >> 3);
            const int slot = t & 7;                    // 16B slot in row
            float4 v = ld4(x + (size_t)(T0 + r) * C_ + k0 + slot * 4);
            const float4 wv = ld4(lnw + k0 + slot * 4);
            v.x *= wv.x; v.y *= wv.y; v.z *= wv.z; v.w *= wv.w;
            const int byteoff = r * 128 + ((slot * 16) ^ ((r & 7) << 4));
            *reinterpret_cast<float4*>(reinterpret_cast<char*>(xs) + byteoff) = v;
        }
        __syncthreads();
        // --- FMA: 4 cols at a time from swizzled LDS; w1 wave-uniform ---
        const float* wbase = w1 + (size_t)k0 * D_ + dh;
#pragma unroll
        for (int c4 = 0; c4 < 8; ++c4) {
            const int byteoff = myr * 128 + ((c4 * 16) ^ ((myr & 7) << 4));
            const float4 xv = *reinterpret_cast<const float4*>(
                reinterpret_cast<const char*>(xs) + byteoff);
            const float* wr = wbase + (size_t)(c4 * 4) * D_;
#pragma unroll
            for (int d = 0; d < 32; ++d)
                acc[d] = fmaf(xv.x, wr[d], acc[d]);
#pragma unroll
            for (int d = 0; d < 32; ++d)
                acc[d] = fmaf(xv.y, wr[D_ + d], acc[d]);
#pragma unroll
            for (int d = 0; d < 32; ++d)
                acc[d] = fmaf(xv.z, wr[2 * D_ + d], acc[d]);
#pragma unroll
            for (int d = 0; d < 32; ++d)
                acc[d] = fmaf(xv.w, wr[3 * D_ + d], acc[d]);
        }
        __syncthreads();
    }
    float* dst = Pp + ((size_t)ks * NT_ + T0 + myr) * D_ + dh;
#pragma unroll
    for (int d4 = 0; d4 < 8; ++d4)
        *reinterpret_cast<float4*>(dst + d4 * 4) =
            make_float4(acc[d4 * 4], acc[d4 * 4 + 1],
                        acc[d4 * 4 + 2], acc[d4 * 4 + 3]);
}

// ---------------------------------------------------------------------------
// K4: per-token decision.  wave per token (lane = d).  grid 8192, block 256.
// ---------------------------------------------------------------------------
__global__ __launch_bounds__(256) void k4_decide(
        const float* __restrict__ Pp, const float* __restrict__ muv,
        const float* __restrict__ rsv, const float* __restrict__ gterm,
        const float* __restrict__ W1s, const float* __restrict__ Bs,
        const float* __restrict__ b1, const float* __restrict__ w2,
        const float* __restrict__ b2, const float* __restrict__ gum,
        float* __restrict__ keep) {
    const int t = threadIdx.x;
    const int lane = t & 63, wv = t >> 6;
    const int token = blockIdx.x * 4 + wv;
    const int b = token >> 10;

    float p = 0.f;
#pragma unroll
    for (int s = 0; s < KS_; ++s)
        p += Pp[((size_t)s * NT_ + token) * D_ + lane];

    const float mu = muv[token], rs = rsv[token];
    float h = rs * (p - mu * W1s[lane]) + Bs[lane] + gterm[b * D_ + lane]
              + b1[lane];
    h = 0.5f * h * (1.f + erff(h * 0.70710678118654752f));   // exact gelu
    float l0 = h * w2[lane * 2];
    float l1 = h * w2[lane * 2 + 1];
#pragma unroll
    for (int o = 32; o > 0; o >>= 1) {
        l0 += __shfl_down(l0, o);
        l1 += __shfl_down(l1, o);
    }
    if (lane == 0) {
        const float z0 = l0 + b2[0] + gum[token * 2];
        const float z1 = l1 + b2[1] + gum[token * 2 + 1];
        keep[token] = (z0 >= z1) ? 1.f : 0.f;   // argmax ties -> index 0
    }
}

// ---------------------------------------------------------------------------
// K5: out = x * keep[token].  grid 32768 (one row/block), block 256.
// ---------------------------------------------------------------------------
__global__ __launch_bounds__(256) void k5_mask(
        const float* __restrict__ x, const float* __restrict__ keep,
        float* __restrict__ out) {
    const int token = blockIdx.x;
    const float kv = keep[token];
    const float4* src = reinterpret_cast<const float4*>(x + (size_t)token * C_);
    float4* dst = reinterpret_cast<float4*>(out + (size_t)token * C_);
    const int t = threadIdx.x;
#pragma unroll
    for (int p = 0; p < 4; ++p) {
        float4 v = src[p * 256 + t];
        v.x *= kv; v.y *= kv; v.z *= kv; v.w *= kv;
        dst[p * 256 + t] = v;
    }
}

// ---------------------------------------------------------------------------
extern "C" void kernel_launch(void* const* d_in, const int* in_sizes, int n_in,
                              void* d_out, int out_size, void* d_ws,
                              size_t ws_size, hipStream_t stream) {
    const float* x   = (const float*)d_in[0];
    const float* gum = (const float*)d_in[1];
    const float* lnw = (const float*)d_in[2];
    const float* lnb = (const float*)d_in[3];
    const float* w1  = (const float*)d_in[4];
    const float* b1  = (const float*)d_in[5];
    const float* w2  = (const float*)d_in[6];
    const float* b2  = (const float*)d_in[7];
    float* out = (float*)d_out;

    float* wsf   = (float*)d_ws;
    float* Pp    = wsf;                                   // 8*32768*64
    float* muv   = Pp + (size_t)KS_ * NT_ * D_;           // 32768
    float* rsv   = muv + NT_;                             // 32768
    float* part  = rsv + NT_;                             // 4096*2048
    float* G     = part + (size_t)4096 * HC_;             // 32*2048
    float* gterm = G + B_ * HC_;                          // 32*64
    float* W1s   = gterm + B_ * D_;                       // 64
    float* Bs    = W1s + D_;                              // 64
    float* keep  = Bs + D_;                               // 32768

    k1_stats<<<4096, 256, 0, stream>>>(x, lnw, lnb, muv, rsv, part);
    k1b_reduce<<<256, 256, 0, stream>>>(part, G);
    k2_small<<<33, 64, 0, stream>>>(G, w1, lnw, lnb, gterm, W1s, Bs);
    k3_gemm<<<KS_ * 256, 256, 0, stream>>>(x, lnw, w1, Pp);
    k4_decide<<<NT_ / 4, 256, 0, stream>>>(Pp, muv, rsv, gterm, W1s, Bs,
                                           b1, w2, b2, gum, keep);
    k5_mask<<<NT_, 256, 0, stream>>>(x, keep, out);
}

// Round 3
// 530.911 us; speedup vs baseline: 1.8187x; 1.8187x over previous
//
#include <hip/hip_runtime.h>
#include <math.h>

#define B_   32
#define N_   1024
#define C_   4096
#define HC_  2048
#define D_   64
#define NT_  32768           // B*N tokens
#define KS_  8               // K splits for the P-GEMM
#define KC_  (HC_ / KS_)     // 256 columns per split
#define BKC_ 32              // K-chunk per staging step

__device__ __forceinline__ float4 ld4(const float* p) {
    return *reinterpret_cast<const float4*>(p);
}

// ---------------------------------------------------------------------------
// K1: per-row LN stats + per-group accumulation of normalized upper half.
// Row data lives in registers across the stats barrier; one barrier per row.
// grid 4096 (= 32 b * 128 groups), block 256.
// ---------------------------------------------------------------------------
__global__ __launch_bounds__(256) void k1_stats(
        const float* __restrict__ x, const float* __restrict__ lnw,
        const float* __restrict__ lnb, float* __restrict__ muv,
        float* __restrict__ rsv, float* __restrict__ part) {
    __shared__ float red[2][4][2];   // [parity][wave][{s,q}]

    const int t = threadIdx.x;
    const int bid = blockIdx.x;
    const int b = bid >> 7;          // batch
    const int g = bid & 127;         // row group (8 rows)

    const float4 wA = ld4(lnw + HC_ + t * 4);
    const float4 wB = ld4(lnw + HC_ + 1024 + t * 4);
    const float4 bA = ld4(lnb + HC_ + t * 4);
    const float4 bB = ld4(lnb + HC_ + 1024 + t * 4);

    float4 gA = make_float4(0.f, 0.f, 0.f, 0.f);
    float4 gB = make_float4(0.f, 0.f, 0.f, 0.f);

    for (int i = 0; i < 8; ++i) {
        const int n = g * 8 + i;
        const float* row = x + (size_t)(b * N_ + n) * C_;
        const float4 v0 = ld4(row + t * 4);
        const float4 v1 = ld4(row + 1024 + t * 4);
        const float4 v2 = ld4(row + 2048 + t * 4);
        const float4 v3 = ld4(row + 3072 + t * 4);

        float s = (v0.x + v0.y + v0.z + v0.w) + (v1.x + v1.y + v1.z + v1.w)
                + (v2.x + v2.y + v2.z + v2.w) + (v3.x + v3.y + v3.z + v3.w);
        float q = v0.x * v0.x + v0.y * v0.y + v0.z * v0.z + v0.w * v0.w;
        q = fmaf(v1.x, v1.x, fmaf(v1.y, v1.y, fmaf(v1.z, v1.z,
            fmaf(v1.w, v1.w, q))));
        q = fmaf(v2.x, v2.x, fmaf(v2.y, v2.y, fmaf(v2.z, v2.z,
            fmaf(v2.w, v2.w, q))));
        q = fmaf(v3.x, v3.x, fmaf(v3.y, v3.y, fmaf(v3.z, v3.z,
            fmaf(v3.w, v3.w, q))));

#pragma unroll
        for (int o = 32; o > 0; o >>= 1) {
            s += __shfl_down(s, o);
            q += __shfl_down(q, o);
        }
        if ((t & 63) == 0) {
            red[i & 1][t >> 6][0] = s;
            red[i & 1][t >> 6][1] = q;
        }
        __syncthreads();
        const float S = red[i & 1][0][0] + red[i & 1][1][0]
                      + red[i & 1][2][0] + red[i & 1][3][0];
        const float Q = red[i & 1][0][1] + red[i & 1][1][1]
                      + red[i & 1][2][1] + red[i & 1][3][1];
        const float mu = S * (1.f / C_);
        const float rs = rsqrtf(Q * (1.f / C_) - mu * mu + 1e-5f);
        if (t == 0) {
            muv[b * N_ + n] = mu;
            rsv[b * N_ + n] = rs;
        }
        gA.x += (v2.x - mu) * rs * wA.x + bA.x;
        gA.y += (v2.y - mu) * rs * wA.y + bA.y;
        gA.z += (v2.z - mu) * rs * wA.z + bA.z;
        gA.w += (v2.w - mu) * rs * wA.w + bA.w;
        gB.x += (v3.x - mu) * rs * wB.x + bB.x;
        gB.y += (v3.y - mu) * rs * wB.y + bB.y;
        gB.z += (v3.z - mu) * rs * wB.z + bB.z;
        gB.w += (v3.w - mu) * rs * wB.w + bB.w;
    }
    float* pp = part + (size_t)bid * HC_;
    *reinterpret_cast<float4*>(pp + t * 4) = gA;
    *reinterpret_cast<float4*>(pp + 1024 + t * 4) = gB;
}

// ---------------------------------------------------------------------------
// K1b: reduce 128 group partials -> G[b][j].  grid 256, block 256.
// ---------------------------------------------------------------------------
__global__ __launch_bounds__(256) void k1b_reduce(
        const float* __restrict__ part, float* __restrict__ G) {
    const int t = threadIdx.x;
    const int b = blockIdx.x >> 3;
    const int j = ((blockIdx.x & 7) << 8) + t;
    float a = 0.f;
    for (int g = 0; g < 128; ++g)
        a += part[(size_t)(b * 128 + g) * HC_ + j];
    G[b * HC_ + j] = a;
}

// ---------------------------------------------------------------------------
// K2: gterm[b,d] (b<32) and W1s/Bs (b==32).  4-way K-split per block.
// grid 33, block 256.
// ---------------------------------------------------------------------------
__global__ __launch_bounds__(256) void k2_small(
        const float* __restrict__ G, const float* __restrict__ w1,
        const float* __restrict__ lnw, const float* __restrict__ lnb,
        float* __restrict__ gterm, float* __restrict__ W1s,
        float* __restrict__ Bs) {
    __shared__ float red[2][4][64];
    const int t = threadIdx.x;
    const int d = t & 63, s = t >> 6;
    const int b = blockIdx.x;
    if (b < B_) {
        float a = 0.f;
        for (int j = s * 512; j < (s + 1) * 512; ++j)
            a = fmaf(G[b * HC_ + j], w1[(size_t)(HC_ + j) * D_ + d], a);
        red[0][s][d] = a;
        __syncthreads();
        if (s == 0)
            gterm[b * D_ + d] = (red[0][0][d] + red[0][1][d] + red[0][2][d]
                                 + red[0][3][d]) * (1.f / N_);
    } else {
        float a = 0.f, c2 = 0.f;
        for (int c = s * 512; c < (s + 1) * 512; ++c) {
            const float wvv = w1[(size_t)c * D_ + d];
            a = fmaf(lnw[c], wvv, a);
            c2 = fmaf(lnb[c], wvv, c2);
        }
        red[0][s][d] = a;
        red[1][s][d] = c2;
        __syncthreads();
        if (s == 0) {
            W1s[d] = red[0][0][d] + red[0][1][d] + red[0][2][d] + red[0][3][d];
            Bs[d]  = red[1][0][d] + red[1][1][d] + red[1][2][d] + red[1][3][d];
        }
    }
}

// ---------------------------------------------------------------------------
// K3: register-tiled GEMM  P[t,d] = sum_c (x[t,c]*lnw[c]) * w1[c,d].
// Block: 256 rows x 64 d x KC=256.  Thread tile: 4 rows x 16 d (acc[64]).
// A staged k-major in LDS with granule-XOR swizzle -> compute read is ONE
// conflict-free ds_read_b128 per k; B reads are all-lane broadcasts.
// grid = KS_*128 = 1024, block 256.
// ---------------------------------------------------------------------------
__global__ __launch_bounds__(256) void k3_gemm(
        const float* __restrict__ x, const float* __restrict__ lnw,
        const float* __restrict__ w1, float* __restrict__ Pp) {
    __shared__ float As[BKC_ * 256];   // 32 KB, transposed + swizzled
    __shared__ float Bs[BKC_ * D_];    // 8 KB

    const int t = threadIdx.x;
    const int mt = blockIdx.x & 127;   // M tile (256 rows)
    const int ks = blockIdx.x >> 7;    // K split
    const int T0 = mt * 256;
    const int kbase = ks * KC_;
    const int rt = t & 63;             // row tile: rows rt*4 .. rt*4+3
    const int dt = t >> 6;             // d tile: cols dt*16 .. dt*16+15
    const int lrow = t >> 3;           // loader row (0..31, +32p)
    const int lq = t & 7;              // loader k-quad

    float acc[64];
#pragma unroll
    for (int i = 0; i < 64; ++i) acc[i] = 0.f;

    for (int kc = 0; kc < KC_; kc += BKC_) {
        const int k0 = kbase + kc;
        // --- stage B: straight copy of w1[k0..k0+31][0..63] (8 KB) ---
        {
            const float4* s4 = reinterpret_cast<const float4*>(
                w1 + (size_t)k0 * D_);
            float4* b4 = reinterpret_cast<float4*>(Bs);
            b4[t] = s4[t];
            b4[256 + t] = s4[256 + t];
        }
        // --- stage A transposed (k-major) + swizzled, folding ln_w ---
        const float4 wv = ld4(lnw + k0 + lq * 4);
#pragma unroll
        for (int p = 0; p < 8; ++p) {
            const int r = lrow + 32 * p;
            float4 v = ld4(x + (size_t)(T0 + r) * C_ + k0 + lq * 4);
            v.x *= wv.x; v.y *= wv.y; v.z *= wv.z; v.w *= wv.w;
            const int g = r >> 2, rm = r & 3;
            const int kb = 4 * lq;
            As[(kb + 0) * 256 + (((g ^ ((kb + 0) & 7)) << 2) + rm)] = v.x;
            As[(kb + 1) * 256 + (((g ^ ((kb + 1) & 7)) << 2) + rm)] = v.y;
            As[(kb + 2) * 256 + (((g ^ ((kb + 2) & 7)) << 2) + rm)] = v.z;
            As[(kb + 3) * 256 + (((g ^ ((kb + 3) & 7)) << 2) + rm)] = v.w;
        }
        __syncthreads();
        // --- outer-product accumulate ---
#pragma unroll 4
        for (int k = 0; k < BKC_; ++k) {
            const float4 a4 = *reinterpret_cast<const float4*>(
                As + k * 256 + ((rt ^ (k & 7)) << 2));
            const float* br = Bs + k * D_ + dt * 16;
            const float4 b0 = ld4(br), b1 = ld4(br + 4),
                         b2 = ld4(br + 8), b3 = ld4(br + 12);
            const float av[4] = {a4.x, a4.y, a4.z, a4.w};
            const float bv[16] = {b0.x, b0.y, b0.z, b0.w,
                                  b1.x, b1.y, b1.z, b1.w,
                                  b2.x, b2.y, b2.z, b2.w,
                                  b3.x, b3.y, b3.z, b3.w};
#pragma unroll
            for (int ri = 0; ri < 4; ++ri)
#pragma unroll
                for (int cj = 0; cj < 16; ++cj)
                    acc[ri * 16 + cj] =
                        fmaf(av[ri], bv[cj], acc[ri * 16 + cj]);
        }
        __syncthreads();
    }
    // --- write out: row rt*4+ri, cols dt*16 .. +15 ---
#pragma unroll
    for (int ri = 0; ri < 4; ++ri) {
        float* dst = Pp + ((size_t)ks * NT_ + T0 + rt * 4 + ri) * D_ + dt * 16;
#pragma unroll
        for (int c = 0; c < 4; ++c)
            *reinterpret_cast<float4*>(dst + c * 4) = make_float4(
                acc[ri * 16 + c * 4], acc[ri * 16 + c * 4 + 1],
                acc[ri * 16 + c * 4 + 2], acc[ri * 16 + c * 4 + 3]);
    }
}

// ---------------------------------------------------------------------------
// K4: per-token decision.  wave per token (lane = d).  grid 8192, block 256.
// ---------------------------------------------------------------------------
__global__ __launch_bounds__(256) void k4_decide(
        const float* __restrict__ Pp, const float* __restrict__ muv,
        const float* __restrict__ rsv, const float* __restrict__ gterm,
        const float* __restrict__ W1s, const float* __restrict__ Bs,
        const float* __restrict__ b1, const float* __restrict__ w2,
        const float* __restrict__ b2, const float* __restrict__ gum,
        float* __restrict__ keep) {
    const int t = threadIdx.x;
    const int lane = t & 63, wv = t >> 6;
    const int token = blockIdx.x * 4 + wv;
    const int b = token >> 10;

    float p = 0.f;
#pragma unroll
    for (int s = 0; s < KS_; ++s)
        p += Pp[((size_t)s * NT_ + token) * D_ + lane];

    const float mu = muv[token], rs = rsv[token];
    float h = rs * (p - mu * W1s[lane]) + Bs[lane] + gterm[b * D_ + lane]
              + b1[lane];
    h = 0.5f * h * (1.f + erff(h * 0.70710678118654752f));   // exact gelu
    float l0 = h * w2[lane * 2];
    float l1 = h * w2[lane * 2 + 1];
#pragma unroll
    for (int o = 32; o > 0; o >>= 1) {
        l0 += __shfl_down(l0, o);
        l1 += __shfl_down(l1, o);
    }
    if (lane == 0) {
        const float z0 = l0 + b2[0] + gum[token * 2];
        const float z1 = l1 + b2[1] + gum[token * 2 + 1];
        keep[token] = (z0 >= z1) ? 1.f : 0.f;   // argmax ties -> index 0
    }
}

// ---------------------------------------------------------------------------
// K5: out = x * keep[token].  grid 32768 (one row/block), block 256.
// ---------------------------------------------------------------------------
__global__ __launch_bounds__(256) void k5_mask(
        const float* __restrict__ x, const float* __restrict__ keep,
        float* __restrict__ out) {
    const int token = blockIdx.x;
    const float kv = keep[token];
    const float4* src = reinterpret_cast<const float4*>(x + (size_t)token * C_);
    float4* dst = reinterpret_cast<float4*>(out + (size_t)token * C_);
    const int t = threadIdx.x;
#pragma unroll
    for (int p = 0; p < 4; ++p) {
        float4 v = src[p * 256 + t];
        v.x *= kv; v.y *= kv; v.z *= kv; v.w *= kv;
        dst[p * 256 + t] = v;
    }
}

// ---------------------------------------------------------------------------
extern "C" void kernel_launch(void* const* d_in, const int* in_sizes, int n_in,
                              void* d_out, int out_size, void* d_ws,
                              size_t ws_size, hipStream_t stream) {
    const float* x   = (const float*)d_in[0];
    const float* gum = (const float*)d_in[1];
    const float* lnw = (const float*)d_in[2];
    const float* lnb = (const float*)d_in[3];
    const float* w1  = (const float*)d_in[4];
    const float* b1  = (const float*)d_in[5];
    const float* w2  = (const float*)d_in[6];
    const float* b2  = (const float*)d_in[7];
    float* out = (float*)d_out;

    float* wsf   = (float*)d_ws;
    float* Pp    = wsf;                                   // 8*32768*64
    float* muv   = Pp + (size_t)KS_ * NT_ * D_;           // 32768
    float* rsv   = muv + NT_;                             // 32768
    float* part  = rsv + NT_;                             // 4096*2048
    float* G     = part + (size_t)4096 * HC_;             // 32*2048
    float* gterm = G + B_ * HC_;                          // 32*64
    float* W1s   = gterm + B_ * D_;                       // 64
    float* Bs    = W1s + D_;                              // 64
    float* keep  = Bs + D_;                               // 32768

    k1_stats<<<4096, 256, 0, stream>>>(x, lnw, lnb, muv, rsv, part);
    k1b_reduce<<<256, 256, 0, stream>>>(part, G);
    k2_small<<<33, 256, 0, stream>>>(G, w1, lnw, lnb, gterm, W1s, Bs);
    k3_gemm<<<KS_ * 128, 256, 0, stream>>>(x, lnw, w1, Pp);
    k4_decide<<<NT_ / 4, 256, 0, stream>>>(Pp, muv, rsv, gterm, W1s, Bs,
                                           b1, w2, b2, gum, keep);
    k5_mask<<<NT_, 256, 0, stream>>>(x, keep, out);
}

// Round 4
// 496.980 us; speedup vs baseline: 1.9429x; 1.0683x over previous
//
#include <hip/hip_runtime.h>
#include <math.h>

#define B_   32
#define N_   1024
#define C_   4096
#define HC_  2048
#define D_   64
#define NT_  32768           // B*N tokens
#define KS_  8               // K splits for the P-GEMM
#define KC_  (HC_ / KS_)     // 256 columns per split
#define BKC_ 32              // K-chunk per staging step

__device__ __forceinline__ float4 ld4(const float* p) {
    return *reinterpret_cast<const float4*>(p);
}

// ---------------------------------------------------------------------------
// K3f: fused GEMM + lower-half stats.
// P[t,d] = sum_c x[t,c] * (lnw[c]*w1[c,d])  (lnw folded into B tile).
// Also accumulates per-row sum / sumsq over this split's 256 columns.
// Block: 256 rows x 64 d; thread tile 4 rows x 16 d (acc[64]).
// A staged RAW, k-major, granule-XOR swizzled -> one ds_read_b128 per k.
// grid = KS_*128 = 1024, block 256.
// ---------------------------------------------------------------------------
__global__ __launch_bounds__(256) void k3_fused(
        const float* __restrict__ x, const float* __restrict__ lnw,
        const float* __restrict__ w1, float* __restrict__ Pp,
        float* __restrict__ sPart, float* __restrict__ qPart) {
    __shared__ float As[BKC_ * 256];   // 32 KB, transposed + swizzled, raw x
    __shared__ float Bs[BKC_ * D_];    // 8 KB, lnw-folded w1

    const int t = threadIdx.x;
    const int mt = blockIdx.x & 127;   // M tile (256 rows)
    const int ks = blockIdx.x >> 7;    // K split
    const int T0 = mt * 256;
    const int kbase = ks * KC_;
    const int rt = t & 63;             // row tile: rows rt*4 .. rt*4+3
    const int dt = t >> 6;             // d tile: cols dt*16 .. dt*16+15
    const int lrow = t >> 3;           // loader row (0..31, +32p)
    const int lq = t & 7;              // loader k-quad

    float acc[64];
#pragma unroll
    for (int i = 0; i < 64; ++i) acc[i] = 0.f;
    float sA[4] = {0.f, 0.f, 0.f, 0.f};
    float qA[4] = {0.f, 0.f, 0.f, 0.f};

    for (int kc = 0; kc < KC_; kc += BKC_) {
        const int k0 = kbase + kc;
        // --- stage B: w1[k0..k0+31][*] scaled by lnw[k] ---
        {
            const float4* s4 = reinterpret_cast<const float4*>(
                w1 + (size_t)k0 * D_);
            float4* b4 = reinterpret_cast<float4*>(Bs);
            const float wk1 = lnw[k0 + (t >> 4)];
            const float wk2 = lnw[k0 + 16 + (t >> 4)];
            float4 v1 = s4[t];
            v1.x *= wk1; v1.y *= wk1; v1.z *= wk1; v1.w *= wk1;
            b4[t] = v1;
            float4 v2 = s4[256 + t];
            v2.x *= wk2; v2.y *= wk2; v2.z *= wk2; v2.w *= wk2;
            b4[256 + t] = v2;
        }
        // --- stage A raw, transposed (k-major) + swizzled ---
#pragma unroll
        for (int p = 0; p < 8; ++p) {
            const int r = lrow + 32 * p;
            const float4 v = ld4(x + (size_t)(T0 + r) * C_ + k0 + lq * 4);
            const int g = r >> 2, rm = r & 3;
            const int kb = 4 * lq;
            As[(kb + 0) * 256 + (((g ^ ((kb + 0) & 7)) << 2) + rm)] = v.x;
            As[(kb + 1) * 256 + (((g ^ ((kb + 1) & 7)) << 2) + rm)] = v.y;
            As[(kb + 2) * 256 + (((g ^ ((kb + 2) & 7)) << 2) + rm)] = v.z;
            As[(kb + 3) * 256 + (((g ^ ((kb + 3) & 7)) << 2) + rm)] = v.w;
        }
        __syncthreads();
        // --- outer-product accumulate (+ stats on dt==0 waves) ---
#pragma unroll 4
        for (int k = 0; k < BKC_; ++k) {
            const float4 a4 = *reinterpret_cast<const float4*>(
                As + k * 256 + ((rt ^ (k & 7)) << 2));
            const float* br = Bs + k * D_ + dt * 16;
            const float4 b0 = ld4(br), b1 = ld4(br + 4),
                         b2 = ld4(br + 8), b3 = ld4(br + 12);
            const float av[4] = {a4.x, a4.y, a4.z, a4.w};
            const float bv[16] = {b0.x, b0.y, b0.z, b0.w,
                                  b1.x, b1.y, b1.z, b1.w,
                                  b2.x, b2.y, b2.z, b2.w,
                                  b3.x, b3.y, b3.z, b3.w};
            if (dt == 0) {          // wave-uniform guard
#pragma unroll
                for (int ri = 0; ri < 4; ++ri) {
                    sA[ri] += av[ri];
                    qA[ri] = fmaf(av[ri], av[ri], qA[ri]);
                }
            }
#pragma unroll
            for (int ri = 0; ri < 4; ++ri)
#pragma unroll
                for (int cj = 0; cj < 16; ++cj)
                    acc[ri * 16 + cj] =
                        fmaf(av[ri], bv[cj], acc[ri * 16 + cj]);
        }
        __syncthreads();
    }
    // --- write P: row rt*4+ri, cols dt*16 .. +15 ---
#pragma unroll
    for (int ri = 0; ri < 4; ++ri) {
        float* dst = Pp + ((size_t)ks * NT_ + T0 + rt * 4 + ri) * D_ + dt * 16;
#pragma unroll
        for (int c = 0; c < 4; ++c)
            *reinterpret_cast<float4*>(dst + c * 4) = make_float4(
                acc[ri * 16 + c * 4], acc[ri * 16 + c * 4 + 1],
                acc[ri * 16 + c * 4 + 2], acc[ri * 16 + c * 4 + 3]);
    }
    if (dt == 0) {
        *reinterpret_cast<float4*>(sPart + (size_t)ks * NT_ + T0 + rt * 4) =
            make_float4(sA[0], sA[1], sA[2], sA[3]);
        *reinterpret_cast<float4*>(qPart + (size_t)ks * NT_ + T0 + rt * 4) =
            make_float4(qA[0], qA[1], qA[2], qA[3]);
    }
}

// ---------------------------------------------------------------------------
// K1u: upper-half read + stats finalize + global-mean accumulation.
// Reads ONLY cols 2048..4095 (268 MB).  Lower-half sums come from
// sPart/qPart (folded in at lanes t<8 before the block reduction).
// grid 4096 (= 32 b * 128 groups of 8 rows), block 256.
// ---------------------------------------------------------------------------
__global__ __launch_bounds__(256) void k1_upper(
        const float* __restrict__ x, const float* __restrict__ lnw,
        const float* __restrict__ lnb, const float* __restrict__ sPart,
        const float* __restrict__ qPart, float* __restrict__ muv,
        float* __restrict__ rsv, float* __restrict__ part) {
    __shared__ float red[2][4][2];   // [parity][wave][{s,q}]

    const int t = threadIdx.x;
    const int bid = blockIdx.x;
    const int b = bid >> 7;          // batch
    const int g = bid & 127;         // row group (8 rows)

    const float4 wA = ld4(lnw + HC_ + t * 4);
    const float4 wB = ld4(lnw + HC_ + 1024 + t * 4);
    const float4 bA = ld4(lnb + HC_ + t * 4);
    const float4 bB = ld4(lnb + HC_ + 1024 + t * 4);

    float4 gA = make_float4(0.f, 0.f, 0.f, 0.f);
    float4 gB = make_float4(0.f, 0.f, 0.f, 0.f);

    for (int i = 0; i < 8; ++i) {
        const int n = g * 8 + i;
        const int tok = b * N_ + n;
        const float* row = x + (size_t)tok * C_;
        const float4 v2 = ld4(row + 2048 + t * 4);
        const float4 v3 = ld4(row + 3072 + t * 4);

        float s = (v2.x + v2.y + v2.z + v2.w) + (v3.x + v3.y + v3.z + v3.w);
        float q = v2.x * v2.x + v2.y * v2.y + v2.z * v2.z + v2.w * v2.w;
        q = fmaf(v3.x, v3.x, fmaf(v3.y, v3.y, fmaf(v3.z, v3.z,
            fmaf(v3.w, v3.w, q))));
        if (t < KS_) {               // fold in lower-half partials
            s += sPart[(size_t)t * NT_ + tok];
            q += qPart[(size_t)t * NT_ + tok];
        }

#pragma unroll
        for (int o = 32; o > 0; o >>= 1) {
            s += __shfl_down(s, o);
            q += __shfl_down(q, o);
        }
        if ((t & 63) == 0) {
            red[i & 1][t >> 6][0] = s;
            red[i & 1][t >> 6][1] = q;
        }
        __syncthreads();
        const float S = red[i & 1][0][0] + red[i & 1][1][0]
                      + red[i & 1][2][0] + red[i & 1][3][0];
        const float Q = red[i & 1][0][1] + red[i & 1][1][1]
                      + red[i & 1][2][1] + red[i & 1][3][1];
        const float mu = S * (1.f / C_);
        const float rs = rsqrtf(Q * (1.f / C_) - mu * mu + 1e-5f);
        if (t == 0) {
            muv[tok] = mu;
            rsv[tok] = rs;
        }
        gA.x += (v2.x - mu) * rs * wA.x + bA.x;
        gA.y += (v2.y - mu) * rs * wA.y + bA.y;
        gA.z += (v2.z - mu) * rs * wA.z + bA.z;
        gA.w += (v2.w - mu) * rs * wA.w + bA.w;
        gB.x += (v3.x - mu) * rs * wB.x + bB.x;
        gB.y += (v3.y - mu) * rs * wB.y + bB.y;
        gB.z += (v3.z - mu) * rs * wB.z + bB.z;
        gB.w += (v3.w - mu) * rs * wB.w + bB.w;
    }
    float* pp = part + (size_t)bid * HC_;
    *reinterpret_cast<float4*>(pp + t * 4) = gA;
    *reinterpret_cast<float4*>(pp + 1024 + t * 4) = gB;
}

// ---------------------------------------------------------------------------
// K1b: reduce 128 group partials -> G[b][j].  grid 256, block 256.
// ---------------------------------------------------------------------------
__global__ __launch_bounds__(256) void k1b_reduce(
        const float* __restrict__ part, float* __restrict__ G) {
    const int t = threadIdx.x;
    const int b = blockIdx.x >> 3;
    const int j = ((blockIdx.x & 7) << 8) + t;
    float a = 0.f;
    for (int g = 0; g < 128; ++g)
        a += part[(size_t)(b * 128 + g) * HC_ + j];
    G[b * HC_ + j] = a;
}

// ---------------------------------------------------------------------------
// K2a: partial GEMVs, 8x parallel over j.  grid 264 (=32*8 + 8), block 256.
// blocks 0..255:  gpart[b][jq][d] over 256 j each (4-way split inside).
// blocks 256..263: Wpart/Bpart over 256 c each.
// ---------------------------------------------------------------------------
__global__ __launch_bounds__(256) void k2a_part(
        const float* __restrict__ G, const float* __restrict__ w1,
        const float* __restrict__ lnw, const float* __restrict__ lnb,
        float* __restrict__ gpart, float* __restrict__ Wpart,
        float* __restrict__ Bpart) {
    __shared__ float red[2][4][64];
    const int t = threadIdx.x;
    const int d = t & 63, s = t >> 6;
    const int blk = blockIdx.x;
    if (blk < 256) {
        const int b = blk >> 3, jq = blk & 7;
        const int j0 = jq * 256 + s * 64;
        float a = 0.f;
        for (int j = j0; j < j0 + 64; ++j)
            a = fmaf(G[b * HC_ + j], w1[(size_t)(HC_ + j) * D_ + d], a);
        red[0][s][d] = a;
        __syncthreads();
        if (s == 0)
            gpart[(size_t)blk * 64 + d] =
                red[0][0][d] + red[0][1][d] + red[0][2][d] + red[0][3][d];
    } else {
        const int wq = blk - 256;
        const int c0 = wq * 256 + s * 64;
        float a = 0.f, c2 = 0.f;
        for (int c = c0; c < c0 + 64; ++c) {
            const float wvv = w1[(size_t)c * D_ + d];
            a = fmaf(lnw[c], wvv, a);
            c2 = fmaf(lnb[c], wvv, c2);
        }
        red[0][s][d] = a;
        red[1][s][d] = c2;
        __syncthreads();
        if (s == 0) {
            Wpart[wq * 64 + d] =
                red[0][0][d] + red[0][1][d] + red[0][2][d] + red[0][3][d];
            Bpart[wq * 64 + d] =
                red[1][0][d] + red[1][1][d] + red[1][2][d] + red[1][3][d];
        }
    }
}

// ---------------------------------------------------------------------------
// K2b: final reduce.  grid 33, block 64.
// ---------------------------------------------------------------------------
__global__ __launch_bounds__(64) void k2b_final(
        const float* __restrict__ gpart, const float* __restrict__ Wpart,
        const float* __restrict__ Bpart, float* __restrict__ gterm,
        float* __restrict__ W1s, float* __restrict__ Bs) {
    const int d = threadIdx.x;
    const int b = blockIdx.x;
    if (b < B_) {
        float a = 0.f;
#pragma unroll
        for (int q = 0; q < 8; ++q)
            a += gpart[(size_t)(b * 8 + q) * 64 + d];
        gterm[b * D_ + d] = a * (1.f / N_);
    } else {
        float a = 0.f, c2 = 0.f;
#pragma unroll
        for (int q = 0; q < 8; ++q) {
            a += Wpart[q * 64 + d];
            c2 += Bpart[q * 64 + d];
        }
        W1s[d] = a;
        Bs[d] = c2;
    }
}

// ---------------------------------------------------------------------------
// K4: per-token decision.  wave per token (lane = d).  grid 8192, block 256.
// ---------------------------------------------------------------------------
__global__ __launch_bounds__(256) void k4_decide(
        const float* __restrict__ Pp, const float* __restrict__ muv,
        const float* __restrict__ rsv, const float* __restrict__ gterm,
        const float* __restrict__ W1s, const float* __restrict__ Bs,
        const float* __restrict__ b1, const float* __restrict__ w2,
        const float* __restrict__ b2, const float* __restrict__ gum,
        float* __restrict__ keep) {
    const int t = threadIdx.x;
    const int lane = t & 63, wv = t >> 6;
    const int token = blockIdx.x * 4 + wv;
    const int b = token >> 10;

    float p = 0.f;
#pragma unroll
    for (int s = 0; s < KS_; ++s)
        p += Pp[((size_t)s * NT_ + token) * D_ + lane];

    const float mu = muv[token], rs = rsv[token];
    float h = rs * (p - mu * W1s[lane]) + Bs[lane] + gterm[b * D_ + lane]
              + b1[lane];
    h = 0.5f * h * (1.f + erff(h * 0.70710678118654752f));   // exact gelu
    float l0 = h * w2[lane * 2];
    float l1 = h * w2[lane * 2 + 1];
#pragma unroll
    for (int o = 32; o > 0; o >>= 1) {
        l0 += __shfl_down(l0, o);
        l1 += __shfl_down(l1, o);
    }
    if (lane == 0) {
        const float z0 = l0 + b2[0] + gum[token * 2];
        const float z1 = l1 + b2[1] + gum[token * 2 + 1];
        keep[token] = (z0 >= z1) ? 1.f : 0.f;   // argmax ties -> index 0
    }
}

// ---------------------------------------------------------------------------
// K5: out = x * keep[token].  grid 32768 (one row/block), block 256.
// ---------------------------------------------------------------------------
__global__ __launch_bounds__(256) void k5_mask(
        const float* __restrict__ x, const float* __restrict__ keep,
        float* __restrict__ out) {
    const int token = blockIdx.x;
    const float kv = keep[token];
    const float4* src = reinterpret_cast<const float4*>(x + (size_t)token * C_);
    float4* dst = reinterpret_cast<float4*>(out + (size_t)token * C_);
    const int t = threadIdx.x;
#pragma unroll
    for (int p = 0; p < 4; ++p) {
        float4 v = src[p * 256 + t];
        v.x *= kv; v.y *= kv; v.z *= kv; v.w *= kv;
        dst[p * 256 + t] = v;
    }
}

// ---------------------------------------------------------------------------
extern "C" void kernel_launch(void* const* d_in, const int* in_sizes, int n_in,
                              void* d_out, int out_size, void* d_ws,
                              size_t ws_size, hipStream_t stream) {
    const float* x   = (const float*)d_in[0];
    const float* gum = (const float*)d_in[1];
    const float* lnw = (const float*)d_in[2];
    const float* lnb = (const float*)d_in[3];
    const float* w1  = (const float*)d_in[4];
    const float* b1  = (const float*)d_in[5];
    const float* w2  = (const float*)d_in[6];
    const float* b2  = (const float*)d_in[7];
    float* out = (float*)d_out;

    float* wsf   = (float*)d_ws;
    float* Pp    = wsf;                                   // 8*32768*64
    float* muv   = Pp + (size_t)KS_ * NT_ * D_;           // 32768
    float* rsv   = muv + NT_;                             // 32768
    float* part  = rsv + NT_;                             // 4096*2048
    float* G     = part + (size_t)4096 * HC_;             // 32*2048
    float* gterm = G + B_ * HC_;                          // 32*64
    float* W1s   = gterm + B_ * D_;                       // 64
    float* Bs    = W1s + D_;                              // 64
    float* keep  = Bs + D_;                               // 32768
    float* sPart = keep + NT_;                            // 8*32768
    float* qPart = sPart + (size_t)KS_ * NT_;             // 8*32768
    float* gpart = qPart + (size_t)KS_ * NT_;             // 256*64
    float* Wpart = gpart + 256 * 64;                      // 8*64
    float* Bpart = Wpart + 8 * 64;                        // 8*64

    k3_fused<<<KS_ * 128, 256, 0, stream>>>(x, lnw, w1, Pp, sPart, qPart);
    k1_upper<<<4096, 256, 0, stream>>>(x, lnw, lnb, sPart, qPart,
                                       muv, rsv, part);
    k1b_reduce<<<256, 256, 0, stream>>>(part, G);
    k2a_part<<<264, 256, 0, stream>>>(G, w1, lnw, lnb, gpart, Wpart, Bpart);
    k2b_final<<<33, 64, 0, stream>>>(gpart, Wpart, Bpart, gterm, W1s, Bs);
    k4_decide<<<NT_ / 4, 256, 0, stream>>>(Pp, muv, rsv, gterm, W1s, Bs,
                                           b1, w2, b2, gum, keep);
    k5_mask<<<NT_, 256, 0, stream>>>(x, keep, out);
}

// Round 5
// 448.483 us; speedup vs baseline: 2.1530x; 1.1081x over previous
//
#include <hip/hip_runtime.h>
#include <math.h>

#define B_   32
#define N_   1024
#define C_   4096
#define HC_  2048
#define D_   64
#define NT_  32768           // B*N tokens
#define KS_  8               // K splits for the P-GEMM
#define KC_  (HC_ / KS_)     // 256 columns per split
#define BKC_ 32              // K-chunk per staging step

__device__ __forceinline__ float4 ld4(const float* p) {
    return *reinterpret_cast<const float4*>(p);
}

// ---------------------------------------------------------------------------
// K3f: fused GEMM + lower-half stats, software-pipelined staging.
// P[t,d] = sum_c x[t,c] * (lnw[c]*w1[c,d])  (lnw folded into B tile).
// Stats accumulated from staging REGISTERS (not in the FMA loop); global
// loads for chunk kc+1 issue before the FMA loop of chunk kc (T14).
// Block: 256 rows x 64 d; thread tile 4 rows x 16 d (acc[64]).
// grid = KS_*128 = 1024, block 256.
// ---------------------------------------------------------------------------
__global__ __launch_bounds__(256) void k3_fused(
        const float* __restrict__ x, const float* __restrict__ lnw,
        const float* __restrict__ w1, float* __restrict__ Pp,
        float* __restrict__ spq) {
    __shared__ float As[BKC_ * 256];   // 32 KB, transposed + swizzled, raw x
    __shared__ float Bsm[BKC_ * D_];   // 8 KB, lnw-folded w1

    const int t = threadIdx.x;
    const int mt = blockIdx.x & 127;   // M tile (256 rows)
    const int ks = blockIdx.x >> 7;    // K split
    const int T0 = mt * 256;
    const int kbase = ks * KC_;
    const int rt = t & 63;             // row tile: rows rt*4 .. rt*4+3
    const int dt = t >> 6;             // d tile: cols dt*16 .. dt*16+15
    const int lrow = t >> 3;           // loader row (0..31, +32p)
    const int lq = t & 7;              // loader k-quad

    float acc[64];
#pragma unroll
    for (int i = 0; i < 64; ++i) acc[i] = 0.f;
    float sRow[8], qRow[8];
#pragma unroll
    for (int p = 0; p < 8; ++p) { sRow[p] = 0.f; qRow[p] = 0.f; }

    // pipeline registers: staged x (8 rows) + staged w1 (2 float4) + lnw
    float4 xv[8];
    float4 wv1, wv2;
    float lw1, lw2;
    {   // prologue: load chunk 0
        const int k0 = kbase;
#pragma unroll
        for (int p = 0; p < 8; ++p)
            xv[p] = ld4(x + (size_t)(T0 + lrow + 32 * p) * C_ + k0 + lq * 4);
        const float4* s4 = reinterpret_cast<const float4*>(
            w1 + (size_t)k0 * D_);
        wv1 = s4[t]; wv2 = s4[256 + t];
        lw1 = lnw[k0 + (t >> 4)];
        lw2 = lnw[k0 + 16 + (t >> 4)];
    }

#pragma unroll 1
    for (int kc = 0; kc < KC_ / BKC_; ++kc) {
        // --- stage current chunk from regs, accumulate stats ---
#pragma unroll
        for (int p = 0; p < 8; ++p) {
            const float4 v = xv[p];
            const int r = lrow + 32 * p;
            const int g = r >> 2, rm = r & 3;
            const int kb = 4 * lq;
            As[(kb + 0) * 256 + (((g ^ ((kb + 0) & 7)) << 2) + rm)] = v.x;
            As[(kb + 1) * 256 + (((g ^ ((kb + 1) & 7)) << 2) + rm)] = v.y;
            As[(kb + 2) * 256 + (((g ^ ((kb + 2) & 7)) << 2) + rm)] = v.z;
            As[(kb + 3) * 256 + (((g ^ ((kb + 3) & 7)) << 2) + rm)] = v.w;
            sRow[p] += (v.x + v.y) + (v.z + v.w);
            qRow[p] = fmaf(v.x, v.x, fmaf(v.y, v.y,
                      fmaf(v.z, v.z, fmaf(v.w, v.w, qRow[p]))));
        }
        {
            float4 v1 = wv1, v2 = wv2;
            v1.x *= lw1; v1.y *= lw1; v1.z *= lw1; v1.w *= lw1;
            v2.x *= lw2; v2.y *= lw2; v2.z *= lw2; v2.w *= lw2;
            float4* b4 = reinterpret_cast<float4*>(Bsm);
            b4[t] = v1;
            b4[256 + t] = v2;
        }
        __syncthreads();
        // --- issue next chunk's global loads (overlap with FMA below) ---
        if (kc + 1 < KC_ / BKC_) {
            const int k1 = kbase + (kc + 1) * BKC_;
#pragma unroll
            for (int p = 0; p < 8; ++p)
                xv[p] = ld4(x + (size_t)(T0 + lrow + 32 * p) * C_
                            + k1 + lq * 4);
            const float4* s4 = reinterpret_cast<const float4*>(
                w1 + (size_t)k1 * D_);
            wv1 = s4[t]; wv2 = s4[256 + t];
            lw1 = lnw[k1 + (t >> 4)];
            lw2 = lnw[k1 + 16 + (t >> 4)];
        }
        // --- pure FMA loop ---
#pragma unroll 4
        for (int k = 0; k < BKC_; ++k) {
            const float4 a4 = *reinterpret_cast<const float4*>(
                As + k * 256 + ((rt ^ (k & 7)) << 2));
            const float* br = Bsm + k * D_ + dt * 16;
            const float4 b0 = ld4(br), b1 = ld4(br + 4),
                         b2 = ld4(br + 8), b3 = ld4(br + 12);
            const float av[4] = {a4.x, a4.y, a4.z, a4.w};
            const float bv[16] = {b0.x, b0.y, b0.z, b0.w,
                                  b1.x, b1.y, b1.z, b1.w,
                                  b2.x, b2.y, b2.z, b2.w,
                                  b3.x, b3.y, b3.z, b3.w};
#pragma unroll
            for (int ri = 0; ri < 4; ++ri)
#pragma unroll
                for (int cj = 0; cj < 16; ++cj)
                    acc[ri * 16 + cj] =
                        fmaf(av[ri], bv[cj], acc[ri * 16 + cj]);
        }
        __syncthreads();
    }
    // --- write P: row rt*4+ri, cols dt*16 .. +15 ---
#pragma unroll
    for (int ri = 0; ri < 4; ++ri) {
        float* dst = Pp + ((size_t)ks * NT_ + T0 + rt * 4 + ri) * D_ + dt * 16;
#pragma unroll
        for (int c = 0; c < 4; ++c)
            *reinterpret_cast<float4*>(dst + c * 4) = make_float4(
                acc[ri * 16 + c * 4], acc[ri * 16 + c * 4 + 1],
                acc[ri * 16 + c * 4 + 2], acc[ri * 16 + c * 4 + 3]);
    }
    // --- reduce + write stats: rows of this loader thread ---
#pragma unroll
    for (int p = 0; p < 8; ++p) {
        float s = sRow[p], q = qRow[p];
        s += __shfl_xor(s, 1); q += __shfl_xor(q, 1);
        s += __shfl_xor(s, 2); q += __shfl_xor(q, 2);
        s += __shfl_xor(s, 4); q += __shfl_xor(q, 4);
        if (lq == 0) {
            const size_t r = (size_t)(T0 + lrow + 32 * p) * 16;
            spq[r + ks] = s;
            spq[r + 8 + ks] = q;
        }
    }
}

// ---------------------------------------------------------------------------
// K1u: upper-half read + stats finalize + global-mean accumulation.
// 32 rows/block (grid 1024).  Lower-half sums come from spq[tok*16]
// (uniform broadcast float4 loads, folded after the block reduction).
// ---------------------------------------------------------------------------
__global__ __launch_bounds__(256) void k1_upper(
        const float* __restrict__ x, const float* __restrict__ lnw,
        const float* __restrict__ lnb, const float* __restrict__ spq,
        float* __restrict__ muv, float* __restrict__ rsv,
        float* __restrict__ part) {
    __shared__ float red[2][4][2];   // [parity][wave][{s,q}]

    const int t = threadIdx.x;
    const int bid = blockIdx.x;
    const int b = bid >> 5;          // batch
    const int g = bid & 31;          // row group (32 rows)

    const float4 wA = ld4(lnw + HC_ + t * 4);
    const float4 wB = ld4(lnw + HC_ + 1024 + t * 4);
    const float4 bA = ld4(lnb + HC_ + t * 4);
    const float4 bB = ld4(lnb + HC_ + 1024 + t * 4);

    float4 gA = make_float4(0.f, 0.f, 0.f, 0.f);
    float4 gB = make_float4(0.f, 0.f, 0.f, 0.f);

    for (int i = 0; i < 32; ++i) {
        const int tok = b * N_ + g * 32 + i;
        const float* row = x + (size_t)tok * C_;
        const float4 v2 = ld4(row + 2048 + t * 4);
        const float4 v3 = ld4(row + 3072 + t * 4);

        float s = (v2.x + v2.y + v2.z + v2.w) + (v3.x + v3.y + v3.z + v3.w);
        float q = v2.x * v2.x + v2.y * v2.y + v2.z * v2.z + v2.w * v2.w;
        q = fmaf(v3.x, v3.x, fmaf(v3.y, v3.y, fmaf(v3.z, v3.z,
            fmaf(v3.w, v3.w, q))));

#pragma unroll
        for (int o = 32; o > 0; o >>= 1) {
            s += __shfl_down(s, o);
            q += __shfl_down(q, o);
        }
        if ((t & 63) == 0) {
            red[i & 1][t >> 6][0] = s;
            red[i & 1][t >> 6][1] = q;
        }
        // uniform broadcast loads of lower-half partials (L2-hot, 2 MB)
        const float4 s0 = ld4(spq + (size_t)tok * 16);
        const float4 s1 = ld4(spq + (size_t)tok * 16 + 4);
        const float4 q0 = ld4(spq + (size_t)tok * 16 + 8);
        const float4 q1 = ld4(spq + (size_t)tok * 16 + 12);
        __syncthreads();
        const float S = red[i & 1][0][0] + red[i & 1][1][0]
                      + red[i & 1][2][0] + red[i & 1][3][0]
                      + (s0.x + s0.y + s0.z + s0.w)
                      + (s1.x + s1.y + s1.z + s1.w);
        const float Q = red[i & 1][0][1] + red[i & 1][1][1]
                      + red[i & 1][2][1] + red[i & 1][3][1]
                      + (q0.x + q0.y + q0.z + q0.w)
                      + (q1.x + q1.y + q1.z + q1.w);
        const float mu = S * (1.f / C_);
        const float rs = rsqrtf(Q * (1.f / C_) - mu * mu + 1e-5f);
        if (t == 0) {
            muv[tok] = mu;
            rsv[tok] = rs;
        }
        gA.x += (v2.x - mu) * rs * wA.x + bA.x;
        gA.y += (v2.y - mu) * rs * wA.y + bA.y;
        gA.z += (v2.z - mu) * rs * wA.z + bA.z;
        gA.w += (v2.w - mu) * rs * wA.w + bA.w;
        gB.x += (v3.x - mu) * rs * wB.x + bB.x;
        gB.y += (v3.y - mu) * rs * wB.y + bB.y;
        gB.z += (v3.z - mu) * rs * wB.z + bB.z;
        gB.w += (v3.w - mu) * rs * wB.w + bB.w;
    }
    float* pp = part + (size_t)bid * HC_;
    *reinterpret_cast<float4*>(pp + t * 4) = gA;
    *reinterpret_cast<float4*>(pp + 1024 + t * 4) = gB;
}

// ---------------------------------------------------------------------------
// K1b: reduce 32 group partials -> G[b][j].  grid 256, block 256.
// ---------------------------------------------------------------------------
__global__ __launch_bounds__(256) void k1b_reduce(
        const float* __restrict__ part, float* __restrict__ G) {
    const int t = threadIdx.x;
    const int b = blockIdx.x >> 3;
    const int j = ((blockIdx.x & 7) << 8) + t;
    float a = 0.f;
    for (int g = 0; g < 32; ++g)
        a += part[(size_t)(b * 32 + g) * HC_ + j];
    G[b * HC_ + j] = a;
}

// ---------------------------------------------------------------------------
// K2a: partial GEMVs, 8x parallel over j.  grid 264, block 256.
// ---------------------------------------------------------------------------
__global__ __launch_bounds__(256) void k2a_part(
        const float* __restrict__ G, const float* __restrict__ w1,
        const float* __restrict__ lnw, const float* __restrict__ lnb,
        float* __restrict__ gpart, float* __restrict__ Wpart,
        float* __restrict__ Bpart) {
    __shared__ float red[2][4][64];
    const int t = threadIdx.x;
    const int d = t & 63, s = t >> 6;
    const int blk = blockIdx.x;
    if (blk < 256) {
        const int b = blk >> 3, jq = blk & 7;
        const int j0 = jq * 256 + s * 64;
        float a = 0.f;
        for (int j = j0; j < j0 + 64; ++j)
            a = fmaf(G[b * HC_ + j], w1[(size_t)(HC_ + j) * D_ + d], a);
        red[0][s][d] = a;
        __syncthreads();
        if (s == 0)
            gpart[(size_t)blk * 64 + d] =
                red[0][0][d] + red[0][1][d] + red[0][2][d] + red[0][3][d];
    } else {
        const int wq = blk - 256;
        const int c0 = wq * 256 + s * 64;
        float a = 0.f, c2 = 0.f;
        for (int c = c0; c < c0 + 64; ++c) {
            const float wvv = w1[(size_t)c * D_ + d];
            a = fmaf(lnw[c], wvv, a);
            c2 = fmaf(lnb[c], wvv, c2);
        }
        red[0][s][d] = a;
        red[1][s][d] = c2;
        __syncthreads();
        if (s == 0) {
            Wpart[wq * 64 + d] =
                red[0][0][d] + red[0][1][d] + red[0][2][d] + red[0][3][d];
            Bpart[wq * 64 + d] =
                red[1][0][d] + red[1][1][d] + red[1][2][d] + red[1][3][d];
        }
    }
}

// ---------------------------------------------------------------------------
// K2b: final reduce.  grid 33, block 64.
// ---------------------------------------------------------------------------
__global__ __launch_bounds__(64) void k2b_final(
        const float* __restrict__ gpart, const float* __restrict__ Wpart,
        const float* __restrict__ Bpart, float* __restrict__ gterm,
        float* __restrict__ W1s, float* __restrict__ Bs) {
    const int d = threadIdx.x;
    const int b = blockIdx.x;
    if (b < B_) {
        float a = 0.f;
#pragma unroll
        for (int q = 0; q < 8; ++q)
            a += gpart[(size_t)(b * 8 + q) * 64 + d];
        gterm[b * D_ + d] = a * (1.f / N_);
    } else {
        float a = 0.f, c2 = 0.f;
#pragma unroll
        for (int q = 0; q < 8; ++q) {
            a += Wpart[q * 64 + d];
            c2 += Bpart[q * 64 + d];
        }
        W1s[d] = a;
        Bs[d] = c2;
    }
}

// ---------------------------------------------------------------------------
// K45: per-token decision + masked copy, one wave per token (barrier-free).
// xor-butterfly so every lane holds the logits.  grid 8192, block 256.
// ---------------------------------------------------------------------------
__global__ __launch_bounds__(256) void k45_decide_mask(
        const float* __restrict__ Pp, const float* __restrict__ muv,
        const float* __restrict__ rsv, const float* __restrict__ gterm,
        const float* __restrict__ W1s, const float* __restrict__ Bs,
        const float* __restrict__ b1, const float* __restrict__ w2,
        const float* __restrict__ b2, const float* __restrict__ gum,
        const float* __restrict__ x, float* __restrict__ out) {
    const int t = threadIdx.x;
    const int lane = t & 63, w = t >> 6;
    const int token = blockIdx.x * 4 + w;
    const int b = token >> 10;

    float p = 0.f;
#pragma unroll
    for (int s = 0; s < KS_; ++s)
        p += Pp[((size_t)s * NT_ + token) * D_ + lane];

    const float mu = muv[token], rs = rsv[token];
    float h = rs * (p - mu * W1s[lane]) + Bs[lane] + gterm[b * D_ + lane]
              + b1[lane];
    h = 0.5f * h * (1.f + erff(h * 0.70710678118654752f));   // exact gelu
    const float2 w2v = *reinterpret_cast<const float2*>(w2 + lane * 2);
    float l0 = h * w2v.x;
    float l1 = h * w2v.y;
#pragma unroll
    for (int o = 1; o < 64; o <<= 1) {
        l0 += __shfl_xor(l0, o);
        l1 += __shfl_xor(l1, o);
    }
    const float z0 = l0 + b2[0] + gum[token * 2];
    const float z1 = l1 + b2[1] + gum[token * 2 + 1];
    const float kv = (z0 >= z1) ? 1.f : 0.f;   // argmax ties -> index 0

    const float4* src = reinterpret_cast<const float4*>(x + (size_t)token * C_);
    float4* dst = reinterpret_cast<float4*>(out + (size_t)token * C_);
#pragma unroll
    for (int c = 0; c < 16; ++c) {
        float4 v = src[c * 64 + lane];
        v.x *= kv; v.y *= kv; v.z *= kv; v.w *= kv;
        dst[c * 64 + lane] = v;
    }
}

// ---------------------------------------------------------------------------
extern "C" void kernel_launch(void* const* d_in, const int* in_sizes, int n_in,
                              void* d_out, int out_size, void* d_ws,
                              size_t ws_size, hipStream_t stream) {
    const float* x   = (const float*)d_in[0];
    const float* gum = (const float*)d_in[1];
    const float* lnw = (const float*)d_in[2];
    const float* lnb = (const float*)d_in[3];
    const float* w1  = (const float*)d_in[4];
    const float* b1  = (const float*)d_in[5];
    const float* w2  = (const float*)d_in[6];
    const float* b2  = (const float*)d_in[7];
    float* out = (float*)d_out;

    float* wsf   = (float*)d_ws;
    float* Pp    = wsf;                                   // 8*32768*64
    float* muv   = Pp + (size_t)KS_ * NT_ * D_;           // 32768
    float* rsv   = muv + NT_;                             // 32768
    float* part  = rsv + NT_;                             // 1024*2048
    float* G     = part + (size_t)1024 * HC_;             // 32*2048
    float* gterm = G + B_ * HC_;                          // 32*64
    float* W1s   = gterm + B_ * D_;                       // 64
    float* Bs    = W1s + D_;                              // 64
    float* spq   = Bs + D_;                               // 32768*16
    float* gpart = spq + (size_t)NT_ * 16;                // 256*64
    float* Wpart = gpart + 256 * 64;                      // 8*64
    float* Bpart = Wpart + 8 * 64;                        // 8*64

    k3_fused<<<KS_ * 128, 256, 0, stream>>>(x, lnw, w1, Pp, spq);
    k1_upper<<<1024, 256, 0, stream>>>(x, lnw, lnb, spq, muv, rsv, part);
    k1b_reduce<<<256, 256, 0, stream>>>(part, G);
    k2a_part<<<264, 256, 0, stream>>>(G, w1, lnw, lnb, gpart, Wpart, Bpart);
    k2b_final<<<33, 64, 0, stream>>>(gpart, Wpart, Bpart, gterm, W1s, Bs);
    k45_decide_mask<<<NT_ / 4, 256, 0, stream>>>(Pp, muv, rsv, gterm, W1s,
                                                 Bs, b1, w2, b2, gum, x, out);
}

// Round 6
// 417.081 us; speedup vs baseline: 2.3151x; 1.0753x over previous
//
#include <hip/hip_runtime.h>
#include <math.h>

#define B_   32
#define N_   1024
#define C_   4096
#define HC_  2048
#define D_   64
#define NT_  32768           // B*N tokens
#define KS_  8               // K splits for the P-GEMM
#define KC_  (HC_ / KS_)     // 256 columns per split
#define BKC_ 32              // K-chunk per staging step

__device__ __forceinline__ float4 ld4(const float* p) {
    return *reinterpret_cast<const float4*>(p);
}

// ---------------------------------------------------------------------------
// K3f: fused GEMM + lower-half stats, software-pipelined staging.
// P[t,d] = sum_c x[t,c] * (lnw[c]*w1[c,d])  (lnw folded into B tile).
// Block: 256 rows x 64 d; thread tile 4 rows x 16 d (acc[64]).
// grid = KS_*128 = 1024, block 256.   [UNCHANGED — control]
// ---------------------------------------------------------------------------
__global__ __launch_bounds__(256) void k3_fused(
        const float* __restrict__ x, const float* __restrict__ lnw,
        const float* __restrict__ w1, float* __restrict__ Pp,
        float* __restrict__ spq) {
    __shared__ float As[BKC_ * 256];   // 32 KB, transposed + swizzled, raw x
    __shared__ float Bsm[BKC_ * D_];   // 8 KB, lnw-folded w1

    const int t = threadIdx.x;
    const int mt = blockIdx.x & 127;   // M tile (256 rows)
    const int ks = blockIdx.x >> 7;    // K split
    const int T0 = mt * 256;
    const int kbase = ks * KC_;
    const int rt = t & 63;             // row tile: rows rt*4 .. rt*4+3
    const int dt = t >> 6;             // d tile: cols dt*16 .. dt*16+15
    const int lrow = t >> 3;           // loader row (0..31, +32p)
    const int lq = t & 7;              // loader k-quad

    float acc[64];
#pragma unroll
    for (int i = 0; i < 64; ++i) acc[i] = 0.f;
    float sRow[8], qRow[8];
#pragma unroll
    for (int p = 0; p < 8; ++p) { sRow[p] = 0.f; qRow[p] = 0.f; }

    float4 xv[8];
    float4 wv1, wv2;
    float lw1, lw2;
    {   // prologue: load chunk 0
        const int k0 = kbase;
#pragma unroll
        for (int p = 0; p < 8; ++p)
            xv[p] = ld4(x + (size_t)(T0 + lrow + 32 * p) * C_ + k0 + lq * 4);
        const float4* s4 = reinterpret_cast<const float4*>(
            w1 + (size_t)k0 * D_);
        wv1 = s4[t]; wv2 = s4[256 + t];
        lw1 = lnw[k0 + (t >> 4)];
        lw2 = lnw[k0 + 16 + (t >> 4)];
    }

#pragma unroll 1
    for (int kc = 0; kc < KC_ / BKC_; ++kc) {
#pragma unroll
        for (int p = 0; p < 8; ++p) {
            const float4 v = xv[p];
            const int r = lrow + 32 * p;
            const int g = r >> 2, rm = r & 3;
            const int kb = 4 * lq;
            As[(kb + 0) * 256 + (((g ^ ((kb + 0) & 7)) << 2) + rm)] = v.x;
            As[(kb + 1) * 256 + (((g ^ ((kb + 1) & 7)) << 2) + rm)] = v.y;
            As[(kb + 2) * 256 + (((g ^ ((kb + 2) & 7)) << 2) + rm)] = v.z;
            As[(kb + 3) * 256 + (((g ^ ((kb + 3) & 7)) << 2) + rm)] = v.w;
            sRow[p] += (v.x + v.y) + (v.z + v.w);
            qRow[p] = fmaf(v.x, v.x, fmaf(v.y, v.y,
                      fmaf(v.z, v.z, fmaf(v.w, v.w, qRow[p]))));
        }
        {
            float4 v1 = wv1, v2 = wv2;
            v1.x *= lw1; v1.y *= lw1; v1.z *= lw1; v1.w *= lw1;
            v2.x *= lw2; v2.y *= lw2; v2.z *= lw2; v2.w *= lw2;
            float4* b4 = reinterpret_cast<float4*>(Bsm);
            b4[t] = v1;
            b4[256 + t] = v2;
        }
        __syncthreads();
        if (kc + 1 < KC_ / BKC_) {
            const int k1 = kbase + (kc + 1) * BKC_;
#pragma unroll
            for (int p = 0; p < 8; ++p)
                xv[p] = ld4(x + (size_t)(T0 + lrow + 32 * p) * C_
                            + k1 + lq * 4);
            const float4* s4 = reinterpret_cast<const float4*>(
                w1 + (size_t)k1 * D_);
            wv1 = s4[t]; wv2 = s4[256 + t];
            lw1 = lnw[k1 + (t >> 4)];
            lw2 = lnw[k1 + 16 + (t >> 4)];
        }
#pragma unroll 4
        for (int k = 0; k < BKC_; ++k) {
            const float4 a4 = *reinterpret_cast<const float4*>(
                As + k * 256 + ((rt ^ (k & 7)) << 2));
            const float* br = Bsm + k * D_ + dt * 16;
            const float4 b0 = ld4(br), b1 = ld4(br + 4),
                         b2 = ld4(br + 8), b3 = ld4(br + 12);
            const float av[4] = {a4.x, a4.y, a4.z, a4.w};
            const float bv[16] = {b0.x, b0.y, b0.z, b0.w,
                                  b1.x, b1.y, b1.z, b1.w,
                                  b2.x, b2.y, b2.z, b2.w,
                                  b3.x, b3.y, b3.z, b3.w};
#pragma unroll
            for (int ri = 0; ri < 4; ++ri)
#pragma unroll
                for (int cj = 0; cj < 16; ++cj)
                    acc[ri * 16 + cj] =
                        fmaf(av[ri], bv[cj], acc[ri * 16 + cj]);
        }
        __syncthreads();
    }
#pragma unroll
    for (int ri = 0; ri < 4; ++ri) {
        float* dst = Pp + ((size_t)ks * NT_ + T0 + rt * 4 + ri) * D_ + dt * 16;
#pragma unroll
        for (int c = 0; c < 4; ++c)
            *reinterpret_cast<float4*>(dst + c * 4) = make_float4(
                acc[ri * 16 + c * 4], acc[ri * 16 + c * 4 + 1],
                acc[ri * 16 + c * 4 + 2], acc[ri * 16 + c * 4 + 3]);
    }
#pragma unroll
    for (int p = 0; p < 8; ++p) {
        float s = sRow[p], q = qRow[p];
        s += __shfl_xor(s, 1); q += __shfl_xor(q, 1);
        s += __shfl_xor(s, 2); q += __shfl_xor(q, 2);
        s += __shfl_xor(s, 4); q += __shfl_xor(q, 4);
        if (lq == 0) {
            const size_t r = (size_t)(T0 + lrow + 32 * p) * 16;
            spq[r + ks] = s;
            spq[r + 8 + ks] = q;
        }
    }
}

// ---------------------------------------------------------------------------
// K1u v2: per-WAVE row processing, barrier-free.
// Each wave owns 8 rows; lane owns 32 upper columns ((m*64+lane)*4+e).
// Stats via 6-step xor-butterfly (all lanes get bitwise-identical sums);
// g-accum in 8 float4 registers; partial written per (block,wave).
// grid 1024 (= 32 b * 32 groups of 32 rows), block 256.
// ---------------------------------------------------------------------------
__global__ __launch_bounds__(256) void k1_upper(
        const float* __restrict__ x, const float* __restrict__ lnw,
        const float* __restrict__ lnb, const float* __restrict__ spq,
        float* __restrict__ muv, float* __restrict__ rsv,
        float* __restrict__ part) {
    const int t = threadIdx.x;
    const int lane = t & 63, w = t >> 6;
    const int bid = blockIdx.x;
    const int b = bid >> 5;          // batch
    const int g = bid & 31;          // 32-row group

    float4 wv[8], bv[8], gacc[8];
#pragma unroll
    for (int m = 0; m < 8; ++m) {
        wv[m] = ld4(lnw + HC_ + (m * 64 + lane) * 4);
        bv[m] = ld4(lnb + HC_ + (m * 64 + lane) * 4);
        gacc[m] = make_float4(0.f, 0.f, 0.f, 0.f);
    }

    for (int i = 0; i < 8; ++i) {
        const int tok = b * N_ + g * 32 + w * 8 + i;
        const float* row = x + (size_t)tok * C_ + HC_;
        float4 v[8];
        float s = 0.f, q = 0.f;
#pragma unroll
        for (int m = 0; m < 8; ++m) {
            v[m] = ld4(row + (m * 64 + lane) * 4);
            s += (v[m].x + v[m].y) + (v[m].z + v[m].w);
            q = fmaf(v[m].x, v[m].x, fmaf(v[m].y, v[m].y,
                fmaf(v[m].z, v[m].z, fmaf(v[m].w, v[m].w, q))));
        }
#pragma unroll
        for (int o = 1; o < 64; o <<= 1) {
            s += __shfl_xor(s, o);
            q += __shfl_xor(q, o);
        }
        // fold lower-half partials (uniform broadcast loads, L2-hot)
        const float4 s0 = ld4(spq + (size_t)tok * 16);
        const float4 s1 = ld4(spq + (size_t)tok * 16 + 4);
        const float4 q0 = ld4(spq + (size_t)tok * 16 + 8);
        const float4 q1 = ld4(spq + (size_t)tok * 16 + 12);
        const float S = s + (s0.x + s0.y + s0.z + s0.w)
                          + (s1.x + s1.y + s1.z + s1.w);
        const float Q = q + (q0.x + q0.y + q0.z + q0.w)
                          + (q1.x + q1.y + q1.z + q1.w);
        const float mu = S * (1.f / C_);
        const float rs = rsqrtf(Q * (1.f / C_) - mu * mu + 1e-5f);
        if (lane == 0) {
            muv[tok] = mu;
            rsv[tok] = rs;
        }
#pragma unroll
        for (int m = 0; m < 8; ++m) {
            gacc[m].x += (v[m].x - mu) * rs * wv[m].x + bv[m].x;
            gacc[m].y += (v[m].y - mu) * rs * wv[m].y + bv[m].y;
            gacc[m].z += (v[m].z - mu) * rs * wv[m].z + bv[m].z;
            gacc[m].w += (v[m].w - mu) * rs * wv[m].w + bv[m].w;
        }
    }
    // partial index: bid*4 + w  (128 partials per batch)
    float* pp = part + (size_t)(bid * 4 + w) * HC_;
#pragma unroll
    for (int m = 0; m < 8; ++m)
        *reinterpret_cast<float4*>(pp + (m * 64 + lane) * 4) = gacc[m];
}

// ---------------------------------------------------------------------------
// K2a: fold partial-reduce (was k1b) + partial GEMVs.
// blocks 0..255: (b, jq) — sum 128 partials for j-range into LDS, then GEMV.
// blocks 256..263: Wpart/Bpart over 256 c each.
// grid 264, block 256.
// ---------------------------------------------------------------------------
__global__ __launch_bounds__(256) void k2a_part(
        const float* __restrict__ part, const float* __restrict__ w1,
        const float* __restrict__ lnw, const float* __restrict__ lnb,
        float* __restrict__ gpart, float* __restrict__ Wpart,
        float* __restrict__ Bpart) {
    __shared__ float Gs[256];
    __shared__ float red[2][4][64];
    const int t = threadIdx.x;
    const int d = t & 63, s = t >> 6;
    const int blk = blockIdx.x;
    if (blk < 256) {
        const int b = blk >> 3, jq = blk & 7;
        const int j = jq * 256 + t;
        float a = 0.f;
        for (int k = 0; k < 128; ++k)
            a += part[(size_t)(b * 128 + k) * HC_ + j];
        Gs[t] = a;
        __syncthreads();
        float acc = 0.f;
        const int j0 = jq * 256 + s * 64;
        for (int jj = 0; jj < 64; ++jj)
            acc = fmaf(Gs[s * 64 + jj],
                       w1[(size_t)(HC_ + j0 + jj) * D_ + d], acc);
        red[0][s][d] = acc;
        __syncthreads();
        if (s == 0)
            gpart[(size_t)blk * 64 + d] =
                red[0][0][d] + red[0][1][d] + red[0][2][d] + red[0][3][d];
    } else {
        const int wq = blk - 256;
        const int c0 = wq * 256 + s * 64;
        float a = 0.f, c2 = 0.f;
        for (int c = c0; c < c0 + 64; ++c) {
            const float wvv = w1[(size_t)c * D_ + d];
            a = fmaf(lnw[c], wvv, a);
            c2 = fmaf(lnb[c], wvv, c2);
        }
        red[0][s][d] = a;
        red[1][s][d] = c2;
        __syncthreads();
        if (s == 0) {
            Wpart[wq * 64 + d] =
                red[0][0][d] + red[0][1][d] + red[0][2][d] + red[0][3][d];
            Bpart[wq * 64 + d] =
                red[1][0][d] + red[1][1][d] + red[1][2][d] + red[1][3][d];
        }
    }
}

// ---------------------------------------------------------------------------
// K2b: final reduce.  grid 33, block 64.
// ---------------------------------------------------------------------------
__global__ __launch_bounds__(64) void k2b_final(
        const float* __restrict__ gpart, const float* __restrict__ Wpart,
        const float* __restrict__ Bpart, float* __restrict__ gterm,
        float* __restrict__ W1s, float* __restrict__ Bs) {
    const int d = threadIdx.x;
    const int b = blockIdx.x;
    if (b < B_) {
        float a = 0.f;
#pragma unroll
        for (int q = 0; q < 8; ++q)
            a += gpart[(size_t)(b * 8 + q) * 64 + d];
        gterm[b * D_ + d] = a * (1.f / N_);
    } else {
        float a = 0.f, c2 = 0.f;
#pragma unroll
        for (int q = 0; q < 8; ++q) {
            a += Wpart[q * 64 + d];
            c2 += Bpart[q * 64 + d];
        }
        W1s[d] = a;
        Bs[d] = c2;
    }
}

// ---------------------------------------------------------------------------
// K45: per-token decision + masked copy, one wave per token (barrier-free).
// Post-butterfly logits are bitwise-identical across lanes -> the keep
// branch is wave-uniform; dropped tokens write zeros WITHOUT reading x.
// grid 8192, block 256.
// ---------------------------------------------------------------------------
__global__ __launch_bounds__(256) void k45_decide_mask(
        const float* __restrict__ Pp, const float* __restrict__ muv,
        const float* __restrict__ rsv, const float* __restrict__ gterm,
        const float* __restrict__ W1s, const float* __restrict__ Bs,
        const float* __restrict__ b1, const float* __restrict__ w2,
        const float* __restrict__ b2, const float* __restrict__ gum,
        const float* __restrict__ x, float* __restrict__ out) {
    const int t = threadIdx.x;
    const int lane = t & 63, w = t >> 6;
    const int token = blockIdx.x * 4 + w;
    const int b = token >> 10;

    float p = 0.f;
#pragma unroll
    for (int s = 0; s < KS_; ++s)
        p += Pp[((size_t)s * NT_ + token) * D_ + lane];

    const float mu = muv[token], rs = rsv[token];
    float h = rs * (p - mu * W1s[lane]) + Bs[lane] + gterm[b * D_ + lane]
              + b1[lane];
    h = 0.5f * h * (1.f + erff(h * 0.70710678118654752f));   // exact gelu
    const float2 w2v = *reinterpret_cast<const float2*>(w2 + lane * 2);
    float l0 = h * w2v.x;
    float l1 = h * w2v.y;
#pragma unroll
    for (int o = 1; o < 64; o <<= 1) {
        l0 += __shfl_xor(l0, o);
        l1 += __shfl_xor(l1, o);
    }
    const float z0 = l0 + b2[0] + gum[token * 2];
    const float z1 = l1 + b2[1] + gum[token * 2 + 1];

    float4* dst = reinterpret_cast<float4*>(out + (size_t)token * C_);
    if (z0 >= z1) {    // keep (argmax ties -> index 0): copy x
        const float4* src =
            reinterpret_cast<const float4*>(x + (size_t)token * C_);
#pragma unroll
        for (int c = 0; c < 16; ++c)
            dst[c * 64 + lane] = src[c * 64 + lane];
    } else {           // drop: write zeros, skip the x read
        const float4 z = make_float4(0.f, 0.f, 0.f, 0.f);
#pragma unroll
        for (int c = 0; c < 16; ++c)
            dst[c * 64 + lane] = z;
    }
}

// ---------------------------------------------------------------------------
extern "C" void kernel_launch(void* const* d_in, const int* in_sizes, int n_in,
                              void* d_out, int out_size, void* d_ws,
                              size_t ws_size, hipStream_t stream) {
    const float* x   = (const float*)d_in[0];
    const float* gum = (const float*)d_in[1];
    const float* lnw = (const float*)d_in[2];
    const float* lnb = (const float*)d_in[3];
    const float* w1  = (const float*)d_in[4];
    const float* b1  = (const float*)d_in[5];
    const float* w2  = (const float*)d_in[6];
    const float* b2  = (const float*)d_in[7];
    float* out = (float*)d_out;

    float* wsf   = (float*)d_ws;
    float* Pp    = wsf;                                   // 8*32768*64
    float* muv   = Pp + (size_t)KS_ * NT_ * D_;           // 32768
    float* rsv   = muv + NT_;                             // 32768
    float* part  = rsv + NT_;                             // 4096*2048
    float* gterm = part + (size_t)4096 * HC_;             // 32*64
    float* W1s   = gterm + B_ * D_;                       // 64
    float* Bs    = W1s + D_;                              // 64
    float* spq   = Bs + D_;                               // 32768*16
    float* gpart = spq + (size_t)NT_ * 16;                // 256*64
    float* Wpart = gpart + 256 * 64;                      // 8*64
    float* Bpart = Wpart + 8 * 64;                        // 8*64

    k3_fused<<<KS_ * 128, 256, 0, stream>>>(x, lnw, w1, Pp, spq);
    k1_upper<<<1024, 256, 0, stream>>>(x, lnw, lnb, spq, muv, rsv, part);
    k2a_part<<<264, 256, 0, stream>>>(part, w1, lnw, lnb,
                                      gpart, Wpart, Bpart);
    k2b_final<<<33, 64, 0, stream>>>(gpart, Wpart, Bpart, gterm, W1s, Bs);
    k45_decide_mask<<<NT_ / 4, 256, 0, stream>>>(Pp, muv, rsv, gterm, W1s,
                                                 Bs, b1, w2, b2, gum, x, out);
}

// Round 7
// 407.671 us; speedup vs baseline: 2.3685x; 1.0231x over previous
//
#include <hip/hip_runtime.h>
#include <math.h>

#define B_   32
#define N_   1024
#define C_   4096
#define HC_  2048
#define D_   64
#define NT_  32768           // B*N tokens
#define KS_  4               // K splits for the P-GEMM
#define KC_  (HC_ / KS_)     // 512 columns per split
#define BKC_ 32              // K-chunk per staging step

__device__ __forceinline__ float4 ld4(const float* p) {
    return *reinterpret_cast<const float4*>(p);
}

// ---------------------------------------------------------------------------
// K3f: fused GEMM + lower-half stats, software-pipelined staging.
// P[t,d] = sum_c x[t,c] * (lnw[c]*w1[c,d])  (lnw folded into B tile).
// Block: 256 rows x 64 d; thread tile 4 rows x 16 d (acc[64]).
// grid = KS_*128 = 512, block 256.
// ---------------------------------------------------------------------------
__global__ __launch_bounds__(256) void k3_fused(
        const float* __restrict__ x, const float* __restrict__ lnw,
        const float* __restrict__ w1, float* __restrict__ Pp,
        float* __restrict__ spq) {
    __shared__ float As[BKC_ * 256];   // 32 KB, transposed + swizzled, raw x
    __shared__ float Bsm[BKC_ * D_];   // 8 KB, lnw-folded w1

    const int t = threadIdx.x;
    const int mt = blockIdx.x & 127;   // M tile (256 rows)
    const int ks = blockIdx.x >> 7;    // K split
    const int T0 = mt * 256;
    const int kbase = ks * KC_;
    const int rt = t & 63;             // row tile: rows rt*4 .. rt*4+3
    const int dt = t >> 6;             // d tile: cols dt*16 .. dt*16+15
    const int lrow = t >> 3;           // loader row (0..31, +32p)
    const int lq = t & 7;              // loader k-quad

    float acc[64];
#pragma unroll
    for (int i = 0; i < 64; ++i) acc[i] = 0.f;
    float sRow[8], qRow[8];
#pragma unroll
    for (int p = 0; p < 8; ++p) { sRow[p] = 0.f; qRow[p] = 0.f; }

    float4 xv[8];
    float4 wv1, wv2;
    float lw1, lw2;
    {   // prologue: load chunk 0
        const int k0 = kbase;
#pragma unroll
        for (int p = 0; p < 8; ++p)
            xv[p] = ld4(x + (size_t)(T0 + lrow + 32 * p) * C_ + k0 + lq * 4);
        const float4* s4 = reinterpret_cast<const float4*>(
            w1 + (size_t)k0 * D_);
        wv1 = s4[t]; wv2 = s4[256 + t];
        lw1 = lnw[k0 + (t >> 4)];
        lw2 = lnw[k0 + 16 + (t >> 4)];
    }

#pragma unroll 1
    for (int kc = 0; kc < KC_ / BKC_; ++kc) {
#pragma unroll
        for (int p = 0; p < 8; ++p) {
            const float4 v = xv[p];
            const int r = lrow + 32 * p;
            const int g = r >> 2, rm = r & 3;
            const int kb = 4 * lq;
            As[(kb + 0) * 256 + (((g ^ ((kb + 0) & 7)) << 2) + rm)] = v.x;
            As[(kb + 1) * 256 + (((g ^ ((kb + 1) & 7)) << 2) + rm)] = v.y;
            As[(kb + 2) * 256 + (((g ^ ((kb + 2) & 7)) << 2) + rm)] = v.z;
            As[(kb + 3) * 256 + (((g ^ ((kb + 3) & 7)) << 2) + rm)] = v.w;
            sRow[p] += (v.x + v.y) + (v.z + v.w);
            qRow[p] = fmaf(v.x, v.x, fmaf(v.y, v.y,
                      fmaf(v.z, v.z, fmaf(v.w, v.w, qRow[p]))));
        }
        {
            float4 v1 = wv1, v2 = wv2;
            v1.x *= lw1; v1.y *= lw1; v1.z *= lw1; v1.w *= lw1;
            v2.x *= lw2; v2.y *= lw2; v2.z *= lw2; v2.w *= lw2;
            float4* b4 = reinterpret_cast<float4*>(Bsm);
            b4[t] = v1;
            b4[256 + t] = v2;
        }
        __syncthreads();
        if (kc + 1 < KC_ / BKC_) {
            const int k1 = kbase + (kc + 1) * BKC_;
#pragma unroll
            for (int p = 0; p < 8; ++p)
                xv[p] = ld4(x + (size_t)(T0 + lrow + 32 * p) * C_
                            + k1 + lq * 4);
            const float4* s4 = reinterpret_cast<const float4*>(
                w1 + (size_t)k1 * D_);
            wv1 = s4[t]; wv2 = s4[256 + t];
            lw1 = lnw[k1 + (t >> 4)];
            lw2 = lnw[k1 + 16 + (t >> 4)];
        }
#pragma unroll 4
        for (int k = 0; k < BKC_; ++k) {
            const float4 a4 = *reinterpret_cast<const float4*>(
                As + k * 256 + ((rt ^ (k & 7)) << 2));
            const float* br = Bsm + k * D_ + dt * 16;
            const float4 b0 = ld4(br), b1 = ld4(br + 4),
                         b2 = ld4(br + 8), b3 = ld4(br + 12);
            const float av[4] = {a4.x, a4.y, a4.z, a4.w};
            const float bv[16] = {b0.x, b0.y, b0.z, b0.w,
                                  b1.x, b1.y, b1.z, b1.w,
                                  b2.x, b2.y, b2.z, b2.w,
                                  b3.x, b3.y, b3.z, b3.w};
#pragma unroll
            for (int ri = 0; ri < 4; ++ri)
#pragma unroll
                for (int cj = 0; cj < 16; ++cj)
                    acc[ri * 16 + cj] =
                        fmaf(av[ri], bv[cj], acc[ri * 16 + cj]);
        }
        __syncthreads();
    }
#pragma unroll
    for (int ri = 0; ri < 4; ++ri) {
        float* dst = Pp + ((size_t)ks * NT_ + T0 + rt * 4 + ri) * D_ + dt * 16;
#pragma unroll
        for (int c = 0; c < 4; ++c)
            *reinterpret_cast<float4*>(dst + c * 4) = make_float4(
                acc[ri * 16 + c * 4], acc[ri * 16 + c * 4 + 1],
                acc[ri * 16 + c * 4 + 2], acc[ri * 16 + c * 4 + 3]);
    }
#pragma unroll
    for (int p = 0; p < 8; ++p) {
        float s = sRow[p], q = qRow[p];
        s += __shfl_xor(s, 1); q += __shfl_xor(q, 1);
        s += __shfl_xor(s, 2); q += __shfl_xor(q, 2);
        s += __shfl_xor(s, 4); q += __shfl_xor(q, 4);
        if (lq == 0) {
            const size_t r = (size_t)(T0 + lrow + 32 * p) * 8;
            spq[r + ks] = s;
            spq[r + 4 + ks] = q;
        }
    }
}

// ---------------------------------------------------------------------------
// K1u: per-WAVE row processing + cross-wave LDS reduction of gacc.
// Each wave owns 8 rows; lane owns 32 upper columns.  Stats via
// xor-butterfly; ONE barrier at the end for the gacc reduction.
// grid 1024 (= 32 b * 32 groups of 32 rows), block 256.
// ---------------------------------------------------------------------------
__global__ __launch_bounds__(256) void k1_upper(
        const float* __restrict__ x, const float* __restrict__ lnw,
        const float* __restrict__ lnb, const float* __restrict__ spq,
        float* __restrict__ muv, float* __restrict__ rsv,
        float* __restrict__ part) {
    __shared__ float sh[4][HC_];     // 32 KB
    const int t = threadIdx.x;
    const int lane = t & 63, w = t >> 6;
    const int bid = blockIdx.x;
    const int b = bid >> 5;          // batch
    const int g = bid & 31;          // 32-row group

    float4 wv[8], bv[8], gacc[8];
#pragma unroll
    for (int m = 0; m < 8; ++m) {
        wv[m] = ld4(lnw + HC_ + (m * 64 + lane) * 4);
        bv[m] = ld4(lnb + HC_ + (m * 64 + lane) * 4);
        gacc[m] = make_float4(0.f, 0.f, 0.f, 0.f);
    }

    for (int i = 0; i < 8; ++i) {
        const int tok = b * N_ + g * 32 + w * 8 + i;
        const float* row = x + (size_t)tok * C_ + HC_;
        float4 v[8];
        float s = 0.f, q = 0.f;
#pragma unroll
        for (int m = 0; m < 8; ++m) {
            v[m] = ld4(row + (m * 64 + lane) * 4);
            s += (v[m].x + v[m].y) + (v[m].z + v[m].w);
            q = fmaf(v[m].x, v[m].x, fmaf(v[m].y, v[m].y,
                fmaf(v[m].z, v[m].z, fmaf(v[m].w, v[m].w, q))));
        }
#pragma unroll
        for (int o = 1; o < 64; o <<= 1) {
            s += __shfl_xor(s, o);
            q += __shfl_xor(q, o);
        }
        // fold lower-half partials (uniform broadcast loads, L2-hot)
        const float4 s0 = ld4(spq + (size_t)tok * 8);
        const float4 q0 = ld4(spq + (size_t)tok * 8 + 4);
        const float S = s + (s0.x + s0.y) + (s0.z + s0.w);
        const float Q = q + (q0.x + q0.y) + (q0.z + q0.w);
        const float mu = S * (1.f / C_);
        const float rs = rsqrtf(Q * (1.f / C_) - mu * mu + 1e-5f);
        if (lane == 0) {
            muv[tok] = mu;
            rsv[tok] = rs;
        }
#pragma unroll
        for (int m = 0; m < 8; ++m) {
            gacc[m].x += (v[m].x - mu) * rs * wv[m].x + bv[m].x;
            gacc[m].y += (v[m].y - mu) * rs * wv[m].y + bv[m].y;
            gacc[m].z += (v[m].z - mu) * rs * wv[m].z + bv[m].z;
            gacc[m].w += (v[m].w - mu) * rs * wv[m].w + bv[m].w;
        }
    }
    // cross-wave reduction: 4 wave-partials -> 1 block partial
#pragma unroll
    for (int m = 0; m < 8; ++m)
        *reinterpret_cast<float4*>(&sh[w][(m * 64 + lane) * 4]) = gacc[m];
    __syncthreads();
    float* pp = part + (size_t)bid * HC_;
#pragma unroll
    for (int m = 0; m < 8; ++m) {
        const int j = (m * 64 + lane) * 4;
        const float4 a0 = ld4(&sh[0][j]);
        const float4 a1 = ld4(&sh[1][j]);
        const float4 a2 = ld4(&sh[2][j]);
        const float4 a3 = ld4(&sh[3][j]);
        float4 r;
        r.x = (a0.x + a1.x) + (a2.x + a3.x);
        r.y = (a0.y + a1.y) + (a2.y + a3.y);
        r.z = (a0.z + a1.z) + (a2.z + a3.z);
        r.w = (a0.w + a1.w) + (a2.w + a3.w);
        if (w == (m & 3))    // spread the 8 stores across the 4 waves
            *reinterpret_cast<float4*>(pp + j) = r;
    }
}

// ---------------------------------------------------------------------------
// K2a: fold partial-reduce + partial GEMVs.
// blocks 0..255: (b, jq) — sum 32 partials for j-range into LDS, then GEMV.
// blocks 256..263: Wpart/Bpart over 256 c each.
// grid 264, block 256.
// ---------------------------------------------------------------------------
__global__ __launch_bounds__(256) void k2a_part(
        const float* __restrict__ part, const float* __restrict__ w1,
        const float* __restrict__ lnw, const float* __restrict__ lnb,
        float* __restrict__ gpart, float* __restrict__ Wpart,
        float* __restrict__ Bpart) {
    __shared__ float Gs[256];
    __shared__ float red[2][4][64];
    const int t = threadIdx.x;
    const int d = t & 63, s = t >> 6;
    const int blk = blockIdx.x;
    if (blk < 256) {
        const int b = blk >> 3, jq = blk & 7;
        const int j = jq * 256 + t;
        float a = 0.f;
        for (int k = 0; k < 32; ++k)
            a += part[(size_t)(b * 32 + k) * HC_ + j];
        Gs[t] = a;
        __syncthreads();
        float acc = 0.f;
        const int j0 = jq * 256 + s * 64;
        for (int jj = 0; jj < 64; ++jj)
            acc = fmaf(Gs[s * 64 + jj],
                       w1[(size_t)(HC_ + j0 + jj) * D_ + d], acc);
        red[0][s][d] = acc;
        __syncthreads();
        if (s == 0)
            gpart[(size_t)blk * 64 + d] =
                red[0][0][d] + red[0][1][d] + red[0][2][d] + red[0][3][d];
    } else {
        const int wq = blk - 256;
        const int c0 = wq * 256 + s * 64;
        float a = 0.f, c2 = 0.f;
        for (int c = c0; c < c0 + 64; ++c) {
            const float wvv = w1[(size_t)c * D_ + d];
            a = fmaf(lnw[c], wvv, a);
            c2 = fmaf(lnb[c], wvv, c2);
        }
        red[0][s][d] = a;
        red[1][s][d] = c2;
        __syncthreads();
        if (s == 0) {
            Wpart[wq * 64 + d] =
                red[0][0][d] + red[0][1][d] + red[0][2][d] + red[0][3][d];
            Bpart[wq * 64 + d] =
                red[1][0][d] + red[1][1][d] + red[1][2][d] + red[1][3][d];
        }
    }
}

// ---------------------------------------------------------------------------
// K2b: final reduce.  grid 33, block 64.
// ---------------------------------------------------------------------------
__global__ __launch_bounds__(64) void k2b_final(
        const float* __restrict__ gpart, const float* __restrict__ Wpart,
        const float* __restrict__ Bpart, float* __restrict__ gterm,
        float* __restrict__ W1s, float* __restrict__ Bs) {
    const int d = threadIdx.x;
    const int b = blockIdx.x;
    if (b < B_) {
        float a = 0.f;
#pragma unroll
        for (int q = 0; q < 8; ++q)
            a += gpart[(size_t)(b * 8 + q) * 64 + d];
        gterm[b * D_ + d] = a * (1.f / N_);
    } else {
        float a = 0.f, c2 = 0.f;
#pragma unroll
        for (int q = 0; q < 8; ++q) {
            a += Wpart[q * 64 + d];
            c2 += Bpart[q * 64 + d];
        }
        W1s[d] = a;
        Bs[d] = c2;
    }
}

// ---------------------------------------------------------------------------
// K45: per-token decision + masked copy, one wave per token (barrier-free).
// Dropped tokens write zeros WITHOUT reading x.  grid 8192, block 256.
// ---------------------------------------------------------------------------
__global__ __launch_bounds__(256) void k45_decide_mask(
        const float* __restrict__ Pp, const float* __restrict__ muv,
        const float* __restrict__ rsv, const float* __restrict__ gterm,
        const float* __restrict__ W1s, const float* __restrict__ Bs,
        const float* __restrict__ b1, const float* __restrict__ w2,
        const float* __restrict__ b2, const float* __restrict__ gum,
        const float* __restrict__ x, float* __restrict__ out) {
    const int t = threadIdx.x;
    const int lane = t & 63, w = t >> 6;
    const int token = blockIdx.x * 4 + w;
    const int b = token >> 10;

    const float2 gv = *reinterpret_cast<const float2*>(gum + token * 2);
    float p = 0.f;
#pragma unroll
    for (int s = 0; s < KS_; ++s)
        p += Pp[((size_t)s * NT_ + token) * D_ + lane];

    const float mu = muv[token], rs = rsv[token];
    float h = rs * (p - mu * W1s[lane]) + Bs[lane] + gterm[b * D_ + lane]
              + b1[lane];
    h = 0.5f * h * (1.f + erff(h * 0.70710678118654752f));   // exact gelu
    const float2 w2v = *reinterpret_cast<const float2*>(w2 + lane * 2);
    float l0 = h * w2v.x;
    float l1 = h * w2v.y;
#pragma unroll
    for (int o = 1; o < 64; o <<= 1) {
        l0 += __shfl_xor(l0, o);
        l1 += __shfl_xor(l1, o);
    }
    const float z0 = l0 + b2[0] + gv.x;
    const float z1 = l1 + b2[1] + gv.y;

    float4* dst = reinterpret_cast<float4*>(out + (size_t)token * C_);
    if (z0 >= z1) {    // keep (argmax ties -> index 0): copy x
        const float4* src =
            reinterpret_cast<const float4*>(x + (size_t)token * C_);
#pragma unroll
        for (int c = 0; c < 16; ++c)
            dst[c * 64 + lane] = src[c * 64 + lane];
    } else {           // drop: write zeros, skip the x read
        const float4 z = make_float4(0.f, 0.f, 0.f, 0.f);
#pragma unroll
        for (int c = 0; c < 16; ++c)
            dst[c * 64 + lane] = z;
    }
}

// ---------------------------------------------------------------------------
extern "C" void kernel_launch(void* const* d_in, const int* in_sizes, int n_in,
                              void* d_out, int out_size, void* d_ws,
                              size_t ws_size, hipStream_t stream) {
    const float* x   = (const float*)d_in[0];
    const float* gum = (const float*)d_in[1];
    const float* lnw = (const float*)d_in[2];
    const float* lnb = (const float*)d_in[3];
    const float* w1  = (const float*)d_in[4];
    const float* b1  = (const float*)d_in[5];
    const float* w2  = (const float*)d_in[6];
    const float* b2  = (const float*)d_in[7];
    float* out = (float*)d_out;

    float* wsf   = (float*)d_ws;
    float* Pp    = wsf;                                   // 4*32768*64
    float* muv   = Pp + (size_t)KS_ * NT_ * D_;           // 32768
    float* rsv   = muv + NT_;                             // 32768
    float* part  = rsv + NT_;                             // 1024*2048
    float* gterm = part + (size_t)1024 * HC_;             // 32*64
    float* W1s   = gterm + B_ * D_;                       // 64
    float* Bs    = W1s + D_;                              // 64
    float* spq   = Bs + D_;                               // 32768*8
    float* gpart = spq + (size_t)NT_ * 8;                 // 256*64
    float* Wpart = gpart + 256 * 64;                      // 8*64
    float* Bpart = Wpart + 8 * 64;                        // 8*64

    k3_fused<<<KS_ * 128, 256, 0, stream>>>(x, lnw, w1, Pp, spq);
    k1_upper<<<1024, 256, 0, stream>>>(x, lnw, lnb, spq, muv, rsv, part);
    k2a_part<<<264, 256, 0, stream>>>(part, w1, lnw, lnb,
                                      gpart, Wpart, Bpart);
    k2b_final<<<33, 64, 0, stream>>>(gpart, Wpart, Bpart, gterm, W1s, Bs);
    k45_decide_mask<<<NT_ / 4, 256, 0, stream>>>(Pp, muv, rsv, gterm, W1s,
                                                 Bs, b1, w2, b2, gum, x, out);
}